// Round 15
// baseline (5069.185 us; speedup 1.0000x reference)
//
#include <hip/hip_runtime.h>
#include <math.h>

#define E_EDGES 160000
#define N_NODES 10000

typedef __attribute__((ext_vector_type(8))) __bf16 bf16x8;
typedef __attribute__((ext_vector_type(4))) float f32x4;
typedef __attribute__((ext_vector_type(4))) unsigned int u32x4;

__device__ __forceinline__ unsigned short f2bf(float x) {
    unsigned u = __float_as_uint(x);
    u += 0x7fff + ((u >> 16) & 1);   // round-to-nearest-even
    return (unsigned short)(u >> 16);
}
__device__ __forceinline__ float bf2f(unsigned short h) {
    return __uint_as_float(((unsigned)h) << 16);
}
__device__ __forceinline__ float siluf(float v) {
    return v / (1.0f + __expf(-v));
}
__device__ __forceinline__ void gload16(const unsigned short* g, unsigned short* l) {
    __builtin_amdgcn_global_load_lds(
        (const __attribute__((address_space(1))) void*)g,
        (__attribute__((address_space(3))) void*)l, 16, 0, 0);
}

// -------------------------------------------------------------------------
// prep (+degree histogram): cutoff + 16-dim two-body rows (bf16, K pad 32)
// -------------------------------------------------------------------------
__global__ __launch_bounds__(256)
void prep_kernel(const int* __restrict__ ei, const float* __restrict__ na,
                 const float* __restrict__ embed, const float* __restrict__ elen,
                 float* __restrict__ cut, unsigned short* __restrict__ A16b,
                 int* __restrict__ deg)
{
    int e = blockIdx.x * blockDim.x + threadIdx.x;
    if (e >= E_EDGES) return;
    float r  = elen[e];
    float x  = r * (1.0f / 6.0f);
    float x2 = x * x;
    float x6 = x2 * x2 * x2;
    float c = 1.0f - 28.0f * x6 + 48.0f * x6 * x - 21.0f * x6 * x2;
    cut[e] = (x < 1.0f) ? c : 0.0f;
    int ctr = ei[e];
    int ngh = ei[E_EDGES + e];
    atomicAdd(&deg[ctr], 1);
    float4 ac = *(const float4*)(na + (size_t)ctr * 4);
    float4 an = *(const float4*)(na + (size_t)ngh * 4);
    float4 b0 = *(const float4*)(embed + (size_t)e * 8);
    float4 b1 = *(const float4*)(embed + (size_t)e * 8 + 4);
    unsigned short* o = A16b + (size_t)e * 32;
    o[0]  = f2bf(ac.x); o[1]  = f2bf(ac.y); o[2]  = f2bf(ac.z); o[3]  = f2bf(ac.w);
    o[4]  = f2bf(an.x); o[5]  = f2bf(an.y); o[6]  = f2bf(an.z); o[7]  = f2bf(an.w);
    o[8]  = f2bf(b0.x); o[9]  = f2bf(b0.y); o[10] = f2bf(b0.z); o[11] = f2bf(b0.w);
    o[12] = f2bf(b1.x); o[13] = f2bf(b1.y); o[14] = f2bf(b1.z); o[15] = f2bf(b1.w);
    #pragma unroll
    for (int i = 16; i < 32; ++i) o[i] = 0;
}

// -------------------------------------------------------------------------
// all 9 weight transposes in one grid; scale folded. Bt[n*Kpad+k]=W[k*N+n]*sc
// -------------------------------------------------------------------------
__global__ __launch_bounds__(256)
void wtrans_all(const float* __restrict__ w0, const float* __restrict__ w1,
                const float* __restrict__ w2, const float* __restrict__ w3,
                const float* __restrict__ w4, const float* __restrict__ w5,
                const float* __restrict__ w6, const float* __restrict__ w7,
                const float* __restrict__ w8, unsigned short* __restrict__ wbuf)
{
    int blk = blockIdx.x;
    const float* W; int K, N, Kpad, Npad; size_t dbase; int lstart; float sc;
    const float s16  = 0.25f;
    const float s128 = 0.088388347648318447f;
    const float s256 = 0.0625f;
    const float s512 = 0.044194173824159223f;
    const float s576 = 0.041666666666666664f;
    if      (blk <   16) { W=w0; K=16;  N=128; Kpad=32;  Npad=128; dbase=0;       lstart=0;    sc=s16;  }
    else if (blk <  144) { W=w1; K=128; N=256; Kpad=128; Npad=256; dbase=4096;    lstart=16;   sc=s128; }
    else if (blk <  656) { W=w2; K=256; N=512; Kpad=256; Npad=512; dbase=36864;   lstart=144;  sc=s256; }
    else if (blk <  912) { W=w3; K=512; N=128; Kpad=512; Npad=128; dbase=167936;  lstart=656;  sc=s512; }
    else if (blk < 2064) { W=w4; K=576; N=512; Kpad=576; Npad=512; dbase=233472;  lstart=912;  sc=s576; }
    else if (blk < 3088) { W=w5; K=512; N=512; Kpad=512; Npad=512; dbase=528384;  lstart=2064; sc=s512; }
    else if (blk < 3344) { W=w6; K=512; N=64;  Kpad=512; Npad=128; dbase=790528;  lstart=3088; sc=s512; }
    else if (blk < 4496) { W=w7; K=576; N=512; Kpad=576; Npad=512; dbase=856064;  lstart=3344; sc=s576; }
    else                 { W=w8; K=512; N=512; Kpad=512; Npad=512; dbase=1150976; lstart=4496; sc=s512; }
    int local = (blk - lstart) * 256 + threadIdx.x;
    int n = local % Npad, k = local / Npad;
    if (k >= Kpad) return;
    float v = (k < K && n < N) ? W[(size_t)k * N + n] * sc : 0.0f;
    wbuf[dbase + (size_t)n * Kpad + k] = f2bf(v);
}

// -------------------------------------------------------------------------
// CSR: scan, fill, wave-bitonic per-segment sort (deterministic)
// -------------------------------------------------------------------------
__global__ __launch_bounds__(1024)
void scan_kernel(const int* __restrict__ deg, int* __restrict__ offs)
{
    __shared__ int part[1024];
    int t = threadIdx.x;
    int base = t * 10;
    int loc[10];
    int s = 0;
    #pragma unroll
    for (int i = 0; i < 10; ++i) {
        int idx = base + i;
        int d = (idx < N_NODES) ? deg[idx] : 0;
        loc[i] = s; s += d;
    }
    part[t] = s;
    __syncthreads();
    for (int o = 1; o < 1024; o <<= 1) {
        int v = (t >= o) ? part[t - o] : 0;
        __syncthreads();
        part[t] += v;
        __syncthreads();
    }
    int excl = (t > 0) ? part[t - 1] : 0;
    #pragma unroll
    for (int i = 0; i < 10; ++i) {
        int idx = base + i;
        if (idx < N_NODES) offs[idx] = excl + loc[i];
    }
    if (t == 1023) offs[N_NODES] = part[1023];
}

__global__ __launch_bounds__(256)
void fill_kernel(const int* __restrict__ ei, const int* __restrict__ offs,
                 int* __restrict__ cnt, int* __restrict__ elist)
{
    int e = blockIdx.x * blockDim.x + threadIdx.x;
    if (e >= E_EDGES) return;
    int c = ei[e];
    int pos = offs[c] + atomicAdd(&cnt[c], 1);
    elist[pos] = e;
}

__global__ __launch_bounds__(256)
void sortseg_kernel(const int* __restrict__ offs, int* __restrict__ elist)
{
    int node = blockIdx.x * 4 + (threadIdx.x >> 6);
    int l = threadIdx.x & 63;
    if (node >= N_NODES) return;
    int b = offs[node], en = offs[node + 1];
    int deg = en - b;
    if (deg <= 1) return;
    if (deg <= 64) {
        int v = (l < deg) ? elist[b + l] : 0x7fffffff;
        #pragma unroll
        for (int k = 2; k <= 64; k <<= 1) {
            #pragma unroll
            for (int j = k >> 1; j > 0; j >>= 1) {
                int o = __shfl_xor(v, j);
                bool dirUp = ((l & k) == 0);
                bool lower = ((l & j) == 0);
                int mn = v < o ? v : o;
                int mx = v < o ? o : v;
                v = (dirUp == lower) ? mn : mx;
            }
        }
        if (l < deg) elist[b + l] = v;
    } else if (l == 0) {
        for (int i = b + 1; i < en; ++i) {
            int v = elist[i];
            int j = i - 1;
            while (j >= b && elist[j] > v) { elist[j + 1] = elist[j]; --j; }
            elist[j + 1] = v;
        }
    }
}

// -------------------------------------------------------------------------
// env gather-sum (plain stores)
// -------------------------------------------------------------------------
__global__ __launch_bounds__(256)
void envgather_kernel(const unsigned short* __restrict__ Wb, int wstride, int woff,
                      const float* __restrict__ ea, const int* __restrict__ offs,
                      const int* __restrict__ elist, float* __restrict__ env)
{
    int n = blockIdx.x * 2 + (threadIdx.x >> 7);
    int t = threadIdx.x & 127;
    if (n >= N_NODES) return;
    int u = t >> 2, comp = t & 3;
    int widx = woff + u * 2 + (comp ? 1 : 0);
    int beg = offs[n], end = offs[n + 1];
    float acc = 0.0f;
    for (int i = beg; i < end; ++i) {
        int e = elist[i];
        float w = bf2f(Wb[(size_t)e * wstride + widx]);
        float a = ea[(size_t)e * 4 + comp];
        acc += a * w;
    }
    env[(size_t)n * 128 + t] = acc * 0.25f;   // 1/sqrt(16)
}

// -------------------------------------------------------------------------
// bf16 MFMA GEMM (round-14): 128x128 tile, BK=32, 4 waves, 3 LDS pairs,
// counted-vmcnt depth-2 pipeline, ONE barrier/iter, XOR swizzle, unpinned.
// -------------------------------------------------------------------------
template<int EPIL>
__global__ __launch_bounds__(256)
void gemm_bf16(const unsigned short* __restrict__ A1,
               int K, const unsigned short* __restrict__ Bt,
               int nx, int ldc, int Nstore,
               unsigned short* __restrict__ Cb)
{
    __shared__ __align__(16) unsigned short SB[3][2][128 * 32];
    const int tid  = threadIdx.x;
    const int lane = tid & 63;
    const int wid  = tid >> 6;
    const int wr   = wid >> 1, wc = wid & 1;
    const int nwg = gridDim.x;
    const int fid = blockIdx.x;
    const int q = nwg >> 3, r = nwg & 7;
    const int xcd = fid & 7, j = fid >> 3;
    const int L = ((xcd < r) ? xcd * (q + 1) : r * (q + 1) + (xcd - r) * q) + j;
    const int bn = (L % nx) * 128;
    const int bm = (L / nx) * 128;

    const int l15 = lane & 15;
    const int l4r = lane >> 2;
    const int sk8 = (((lane & 3) ^ ((lane >> 3) & 3)) << 3);
    const int rk8 = ((((lane >> 4) ^ ((l15 >> 1) & 3)) & 3) << 3);
    const int T   = K >> 5;

    f32x4 acc[4][4] = {};

    auto stage = [&](int t, int b) {
        int k0 = t << 5;
        #pragma unroll
        for (int i = 0; i < 2; ++i) {
            int ch  = (wid << 1) + i;
            int row = (ch << 4) + l4r;
            gload16(A1 + (size_t)(bm + row) * K + k0 + sk8, &SB[b][0][ch << 9]);
            gload16(Bt + (size_t)(bn + row) * K + k0 + sk8, &SB[b][1][ch << 9]);
        }
    };

    stage(0, 0);
    if (T >= 2) stage(1, 1);

    for (int t = 0; t < T; ++t) {
        if (t < T - 1) asm volatile("s_waitcnt vmcnt(4)" ::: "memory");
        else           asm volatile("s_waitcnt vmcnt(0)" ::: "memory");
        __builtin_amdgcn_s_barrier();
        __builtin_amdgcn_sched_barrier(0);

        if (t + 2 < T) stage(t + 2, (t + 2) % 3);

        const unsigned short* As = &SB[t % 3][0][0];
        const unsigned short* Bs = &SB[t % 3][1][0];
        bf16x8 af[4], bfr[4];
        #pragma unroll
        for (int m = 0; m < 4; ++m)
            af[m] = __builtin_bit_cast(bf16x8, *(const u32x4*)&As[(wr * 64 + m * 16 + l15) * 32 + rk8]);
        #pragma unroll
        for (int n = 0; n < 4; ++n)
            bfr[n] = __builtin_bit_cast(bf16x8, *(const u32x4*)&Bs[(wc * 64 + n * 16 + l15) * 32 + rk8]);

        __builtin_amdgcn_s_setprio(1);
        #pragma unroll
        for (int m = 0; m < 4; ++m)
            #pragma unroll
            for (int n = 0; n < 4; ++n)
                acc[m][n] = __builtin_amdgcn_mfma_f32_16x16x32_bf16(af[m], bfr[n], acc[m][n], 0, 0, 0);
        __builtin_amdgcn_s_setprio(0);
    }

    #pragma unroll
    for (int m = 0; m < 4; ++m) {
        int rbase = bm + wr * 64 + m * 16 + ((lane >> 4) << 2);
        #pragma unroll
        for (int n = 0; n < 4; ++n) {
            int col = bn + wc * 64 + n * 16 + l15;
            if (col < Nstore) {
                #pragma unroll
                for (int rr = 0; rr < 4; ++rr) {
                    int row = rbase + rr;
                    Cb[(size_t)row * ldc + col] = f2bf(acc[m][n][rr]);
                }
            }
        }
    }
}

// -------------------------------------------------------------------------
// FUSED two-body MLP (round-10 proven): Lb = cut * (silu(silu(A16@W0)@W1)@W2)
// -------------------------------------------------------------------------
__global__ __launch_bounds__(512)
void mlp2b(const unsigned short* __restrict__ A16b,
           const unsigned short* __restrict__ W0t,   // [128][32]
           const unsigned short* __restrict__ W1t,   // [256][128]
           const unsigned short* __restrict__ W2t,   // [512][256]
           const float* __restrict__ cut, unsigned short* __restrict__ Lb)
{
    __shared__ __align__(16) unsigned short SA[64 * 32];
    __shared__ __align__(16) unsigned short H1[64 * 128];
    __shared__ __align__(16) unsigned short H2[64 * 256];
    const int tid  = threadIdx.x;
    const int lane = tid & 63;
    const int wid  = tid >> 6;
    const int l15  = lane & 15;
    const int l4r  = lane >> 2;
    const int lk8  = (lane >> 4) << 3;
    const int sk8  = (((lane & 3) ^ ((lane >> 3) & 3)) << 3);
    const int rk8  = ((((lane >> 4) ^ ((l15 >> 1) & 3)) & 3) << 3);
    const int bm   = blockIdx.x * 64;
    const int hrow4 = (lane >> 4) << 2;

    if (wid < 4) {
        int row = (wid << 4) + l4r;
        gload16(A16b + (size_t)(bm + row) * 32 + sk8, &SA[wid << 9]);
    }
    asm volatile("s_waitcnt vmcnt(0)" ::: "memory");
    __builtin_amdgcn_s_barrier();
    __builtin_amdgcn_sched_barrier(0);

    // ---- stage A: H1[64][128] = silu(A @ W0^T)
    {
        int hc = wid * 16 + l15;
        bf16x8 wf = __builtin_bit_cast(bf16x8, *(const u32x4*)(W0t + (size_t)hc * 32 + lk8));
        #pragma unroll
        for (int mi = 0; mi < 4; ++mi) {
            bf16x8 af = __builtin_bit_cast(bf16x8, *(const u32x4*)&SA[(mi * 16 + l15) * 32 + rk8]);
            f32x4 a = {};
            a = __builtin_amdgcn_mfma_f32_16x16x32_bf16(af, wf, a, 0, 0, 0);
            #pragma unroll
            for (int rr = 0; rr < 4; ++rr) {
                int er = mi * 16 + hrow4 + rr;
                H1[er * 128 + (((hc >> 3) ^ (er & 7)) << 3) + (hc & 7)] = f2bf(siluf(a[rr]));
            }
        }
    }
    asm volatile("s_waitcnt lgkmcnt(0)" ::: "memory");
    __builtin_amdgcn_s_barrier();
    __builtin_amdgcn_sched_barrier(0);

    // ---- stage B: H2[64][256] = silu(H1 @ W1^T)
    {
        f32x4 acc[4][2] = {};
        #pragma unroll
        for (int kt = 0; kt < 4; ++kt) {
            bf16x8 hf[4], wf[2];
            #pragma unroll
            for (int fa = 0; fa < 4; ++fa) {
                int er = fa * 16 + l15;
                int slotp = (kt * 4 + (lane >> 4)) ^ (er & 7);
                hf[fa] = __builtin_bit_cast(bf16x8, *(const u32x4*)&H1[er * 128 + slotp * 8]);
            }
            #pragma unroll
            for (int fb = 0; fb < 2; ++fb) {
                int hc = wid * 32 + fb * 16 + l15;
                wf[fb] = __builtin_bit_cast(bf16x8, *(const u32x4*)(W1t + (size_t)hc * 128 + kt * 32 + lk8));
            }
            #pragma unroll
            for (int fa = 0; fa < 4; ++fa)
                #pragma unroll
                for (int fb = 0; fb < 2; ++fb)
                    acc[fa][fb] = __builtin_amdgcn_mfma_f32_16x16x32_bf16(hf[fa], wf[fb], acc[fa][fb], 0, 0, 0);
        }
        asm volatile("s_waitcnt lgkmcnt(0)" ::: "memory");
        __builtin_amdgcn_s_barrier();
        #pragma unroll
        for (int fa = 0; fa < 4; ++fa)
            #pragma unroll
            for (int fb = 0; fb < 2; ++fb)
                #pragma unroll
                for (int rr = 0; rr < 4; ++rr) {
                    int er = fa * 16 + hrow4 + rr;
                    int hc = wid * 32 + fb * 16 + l15;
                    H2[er * 256 + (((hc >> 3) ^ (er & 7)) << 3) + (hc & 7)] = f2bf(siluf(acc[fa][fb][rr]));
                }
    }
    asm volatile("s_waitcnt lgkmcnt(0)" ::: "memory");
    __builtin_amdgcn_s_barrier();
    __builtin_amdgcn_sched_barrier(0);

    // ---- stage C: O[64][512] = cut * (H2 @ W2^T)
    f32x4 acc[4][4] = {};
    #pragma unroll 1
    for (int kt = 0; kt < 8; ++kt) {
        bf16x8 hf[4], wf[4];
        #pragma unroll
        for (int fa = 0; fa < 4; ++fa) {
            int er = fa * 16 + l15;
            int slotp = (kt * 4 + (lane >> 4)) ^ (er & 7);
            hf[fa] = __builtin_bit_cast(bf16x8, *(const u32x4*)&H2[er * 256 + slotp * 8]);
        }
        #pragma unroll
        for (int fb = 0; fb < 4; ++fb) {
            int oc = wid * 64 + fb * 16 + l15;
            wf[fb] = __builtin_bit_cast(bf16x8, *(const u32x4*)(W2t + (size_t)oc * 256 + kt * 32 + lk8));
        }
        __builtin_amdgcn_s_setprio(1);
        #pragma unroll
        for (int fa = 0; fa < 4; ++fa)
            #pragma unroll
            for (int fb = 0; fb < 4; ++fb)
                acc[fa][fb] = __builtin_amdgcn_mfma_f32_16x16x32_bf16(hf[fa], wf[fb], acc[fa][fb], 0, 0, 0);
        __builtin_amdgcn_s_setprio(0);
    }
    #pragma unroll
    for (int fa = 0; fa < 4; ++fa) {
        int rbase = bm + fa * 16 + hrow4;
        #pragma unroll
        for (int fb = 0; fb < 4; ++fb) {
            int col = wid * 64 + fb * 16 + l15;
            #pragma unroll
            for (int rr = 0; rr < 4; ++rr) {
                int row = rbase + rr;
                Lb[(size_t)row * 512 + col] = f2bf(acc[fa][fb][rr] * cut[row]);
            }
        }
    }
}

// -------------------------------------------------------------------------
// FUSED two-layer MLP, half-H K-split: 128 rows, 8 waves, LDS = 64KB Hl +
// 16KB SA = 80KB -> 2 blocks/CU (4 waves/SIMD). Stage 2 runs in two K-halves;
// waves 0-3 publish H cols 0-255 first, waves 4-7 publish cols 256-511 after
// the first half's reads complete. Same swizzle geometry as proven kernels.
// EPIL2: 3 = resnet1 -> Lb bf16 (in-place), 4 = resnet2 -> L f32
// -------------------------------------------------------------------------
template<int EPIL2>
__global__ __launch_bounds__(512, 4)
void fused_mlp(const unsigned short* __restrict__ A1,   // Lb [E,512]
               const unsigned short* __restrict__ A2,   // scalb [E,64]
               const unsigned short* __restrict__ W1t,  // [512][576]
               const unsigned short* __restrict__ W2t,  // [512][512]
               float* __restrict__ Cf, unsigned short* __restrict__ Cb,
               const float* __restrict__ cut, const float* __restrict__ rp)
{
    __shared__ __align__(16) unsigned short Hl[128 * 256];   // 64 KB half-H slab
    __shared__ __align__(16) unsigned short SA[2][128 * 32]; // 2 x 8 KB A staging
    const int tid  = threadIdx.x;
    const int lane = tid & 63;
    const int wid  = tid >> 6;            // 0..7
    const int l15  = lane & 15;
    const int l4r  = lane >> 2;
    const int lk8  = (lane >> 4) << 3;    // k sub-offset (shorts)
    const int sk8  = (((lane & 3) ^ ((lane >> 3) & 3)) << 3);
    const int rk8  = ((((lane >> 4) ^ ((l15 >> 1) & 3)) & 3) << 3);
    const int bm   = blockIdx.x * 128;
    const int col0 = wid * 64;
    const int hrow4 = (lane >> 4) << 2;

    auto stageA = [&](int t, int b) {
        int k0 = t << 5;
        int row = (wid << 4) + l4r;
        const unsigned short* gp;
        if (k0 < 512) gp = A1 + (size_t)(bm + row) * 512 + k0 + sk8;
        else          gp = A2 + (size_t)(bm + row) * 64 + (k0 - 512) + sk8;
        gload16(gp, &SA[b][wid << 9]);
    };

    f32x4 acc1[8][4] = {};
    stageA(0, 0);

    // ---- stage 1: acc1 = A @ W1^T  (depth-1 SA pipeline, W1 from L2)
    for (int t = 0; t < 18; ++t) {
        asm volatile("s_waitcnt vmcnt(0)" ::: "memory");
        __builtin_amdgcn_s_barrier();
        __builtin_amdgcn_sched_barrier(0);

        if (t + 1 < 18) stageA(t + 1, (t + 1) & 1);

        const unsigned short* As = &SA[t & 1][0];
        int k0 = t << 5;
        bf16x8 af[8], wf[4];
        #pragma unroll
        for (int mi = 0; mi < 8; ++mi)
            af[mi] = __builtin_bit_cast(bf16x8, *(const u32x4*)&As[(mi * 16 + l15) * 32 + rk8]);
        #pragma unroll
        for (int ni = 0; ni < 4; ++ni) {
            int hc = col0 + ni * 16 + l15;
            wf[ni] = __builtin_bit_cast(bf16x8, *(const u32x4*)(W1t + (size_t)hc * 576 + k0 + lk8));
        }

        __builtin_amdgcn_s_setprio(1);
        #pragma unroll
        for (int mi = 0; mi < 8; ++mi)
            #pragma unroll
            for (int ni = 0; ni < 4; ++ni)
                acc1[mi][ni] = __builtin_amdgcn_mfma_f32_16x16x32_bf16(af[mi], wf[ni], acc1[mi][ni], 0, 0, 0);
        __builtin_amdgcn_s_setprio(0);
    }

    // publish half-H helper: slab col sc = hc - base (0..255), swizzled
    auto writeHalf = [&](int base) {
        #pragma unroll
        for (int mi = 0; mi < 8; ++mi)
            #pragma unroll
            for (int ni = 0; ni < 4; ++ni)
                #pragma unroll
                for (int rr = 0; rr < 4; ++rr) {
                    int er = mi * 16 + hrow4 + rr;
                    int sc = col0 - base + ni * 16 + l15;
                    Hl[er * 256 + (((sc >> 3) ^ (er & 7)) << 3) + (sc & 7)] = f2bf(siluf(acc1[mi][ni][rr]));
                }
    };
    // stage-2 quarter-K iteration (ktL = slot index within current half)
    f32x4 acc2[8][4] = {};
    auto stage2iter = [&](int kt, int ktL) {
        bf16x8 hf[8], w2f[4];
        #pragma unroll
        for (int fa = 0; fa < 8; ++fa) {
            int er = fa * 16 + l15;
            int slotp = (ktL * 4 + (lane >> 4)) ^ (er & 7);
            hf[fa] = __builtin_bit_cast(bf16x8, *(const u32x4*)&Hl[er * 256 + slotp * 8]);
        }
        #pragma unroll
        for (int fb = 0; fb < 4; ++fb) {
            int oc = col0 + fb * 16 + l15;
            w2f[fb] = __builtin_bit_cast(bf16x8, *(const u32x4*)(W2t + (size_t)oc * 512 + kt * 32 + lk8));
        }
        __builtin_amdgcn_s_setprio(1);
        #pragma unroll
        for (int fa = 0; fa < 8; ++fa)
            #pragma unroll
            for (int fb = 0; fb < 4; ++fb)
                acc2[fa][fb] = __builtin_amdgcn_mfma_f32_16x16x32_bf16(hf[fa], w2f[fb], acc2[fa][fb], 0, 0, 0);
        __builtin_amdgcn_s_setprio(0);
    };

    // ---- half 1: waves 0-3 publish H[:,0:256]
    if (wid < 4) writeHalf(0);
    asm volatile("s_waitcnt lgkmcnt(0)" ::: "memory");
    __builtin_amdgcn_s_barrier();
    __builtin_amdgcn_sched_barrier(0);
    #pragma unroll 1
    for (int kt = 0; kt < 8; ++kt) stage2iter(kt, kt);
    asm volatile("s_waitcnt lgkmcnt(0)" ::: "memory");
    __builtin_amdgcn_s_barrier();        // all half-1 reads retired
    __builtin_amdgcn_sched_barrier(0);

    // ---- half 2: waves 4-7 publish H[:,256:512]
    if (wid >= 4) writeHalf(256);
    asm volatile("s_waitcnt lgkmcnt(0)" ::: "memory");
    __builtin_amdgcn_s_barrier();
    __builtin_amdgcn_sched_barrier(0);
    #pragma unroll 1
    for (int kt = 8; kt < 16; ++kt) stage2iter(kt, kt - 8);

    // --- resnet epilogue (coalesced)
    float c0 = __expf(rp[0]), c1 = __expf(rp[1]), c2 = __expf(rp[2]);
    #pragma unroll
    for (int fa = 0; fa < 8; ++fa) {
        int rbase = bm + fa * 16 + hrow4;
        #pragma unroll
        for (int fb = 0; fb < 4; ++fb) {
            int col = col0 + fb * 16 + l15;
            #pragma unroll
            for (int rr = 0; rr < 4; ++rr) {
                int row = rbase + rr;
                float v = acc2[fa][fb][rr];
                size_t off2 = (size_t)row * 512 + col;
                if (EPIL2 == 3) {
                    float old = bf2f(Cb[off2]);
                    v = (c0 * old + c1 * v * cut[row]) * rsqrtf(c0 * c0 + c1 * c1);
                    Cb[off2] = f2bf(v);
                } else {
                    float old = bf2f(Cb[off2]);
                    float n2 = c0 * c0 + c1 * c1;
                    v = (sqrtf(n2) * old + c2 * v * cut[row]) * rsqrtf(n2 + c2 * c2);
                    Cf[off2] = v;
                }
            }
        }
    }
}

// -------------------------------------------------------------------------
// TP0 + e3nn Linear; Ws/Wv staged in LDS with alpha folded
// -------------------------------------------------------------------------
__global__ __launch_bounds__(256)
void tp0_kernel(const unsigned short* __restrict__ W0b, const float* __restrict__ ea,
                const float* __restrict__ env, const int* __restrict__ ei,
                const float* __restrict__ Ws, const float* __restrict__ Wv,
                unsigned short* __restrict__ scalb, unsigned short* __restrict__ feat2b)
{
    __shared__ float sc[8][64];
    __shared__ float xv[8][64][3];
    __shared__ float Wsl[2048];
    __shared__ float Wvl[2048];
    int tid = threadIdx.x;
    const float alpha = 0.125f;  // 1/sqrt(2U)
    #pragma unroll
    for (int i = 0; i < 8; ++i) {
        Wsl[tid + i * 256] = Ws[tid + i * 256] * alpha;
        Wvl[tid + i * 256] = Wv[tid + i * 256] * alpha;
    }
    int le = tid >> 5;
    int u  = tid & 31;
    int e  = blockIdx.x * 8 + le;
    int c  = ei[e];
    float4 a = *(const float4*)(ea + (size_t)e * 4);
    const float* ep = env + (size_t)c * 128 + u * 4;
    float e0 = ep[0], e1 = ep[1], e2 = ep[2], e3 = ep[3];
    float wf0 = bf2f(W0b[(size_t)e * 128 + u * 2]);
    float wf1 = bf2f(W0b[(size_t)e * 128 + u * 2 + 1]);
    float f0 = a.x * wf0;
    float f1 = a.y * wf1, f2 = a.z * wf1, f3 = a.w * wf1;
    const float rs3 = 0.57735026918962576f;
    float t0 = f0 * e0;
    float t1 = (f1 * e1 + f2 * e2 + f3 * e3) * rs3;
    scalb[(size_t)e * 64 + u]      = f2bf(t0);
    scalb[(size_t)e * 64 + 32 + u] = f2bf(t1);
    sc[le][u]      = t0;
    sc[le][32 + u] = t1;
    xv[le][u][0] = f0 * e1; xv[le][u][1] = f0 * e2; xv[le][u][2] = f0 * e3;
    xv[le][32 + u][0] = f1 * e0; xv[le][32 + u][1] = f2 * e0; xv[le][32 + u][2] = f3 * e0;
    __syncthreads();
    float ys = 0.0f, yv0 = 0.0f, yv1 = 0.0f, yv2 = 0.0f;
    #pragma unroll 8
    for (int k = 0; k < 64; ++k) {
        float ws = Wsl[k * 32 + u];
        float wv = Wvl[k * 32 + u];
        ys  = fmaf(sc[le][k], ws, ys);
        yv0 = fmaf(xv[le][k][0], wv, yv0);
        yv1 = fmaf(xv[le][k][1], wv, yv1);
        yv2 = fmaf(xv[le][k][2], wv, yv2);
    }
    ushort4 ov;
    ov.x = f2bf(ys);
    ov.y = f2bf(yv0);
    ov.z = f2bf(yv1);
    ov.w = f2bf(yv2);
    *(ushort4*)(feat2b + (size_t)e * 128 + u * 4) = ov;
}

// -------------------------------------------------------------------------
// TP1 (scalar outputs only) -> scalars2 bf16 [E,64]
// -------------------------------------------------------------------------
__global__ __launch_bounds__(256)
void tp1_kernel(const unsigned short* __restrict__ feat2b, const float* __restrict__ env,
                const int* __restrict__ ei, unsigned short* __restrict__ scalb)
{
    int idx = blockIdx.x * blockDim.x + threadIdx.x;
    if (idx >= E_EDGES * 32) return;
    int e = idx >> 5, u = idx & 31;
    int c = ei[e];
    const float* ep = env + (size_t)c * 128 + u * 4;
    ushort4 f4 = *(const ushort4*)(feat2b + (size_t)e * 128 + u * 4);
    float fx = bf2f(f4.x), fy = bf2f(f4.y), fz = bf2f(f4.z), fw = bf2f(f4.w);
    const float rs3 = 0.57735026918962576f;
    float t0 = fx * ep[0];
    float t1 = (fy * ep[1] + fz * ep[2] + fw * ep[3]) * rs3;
    scalb[(size_t)e * 64 + u]      = f2bf(t0);
    scalb[(size_t)e * 64 + 32 + u] = f2bf(t1);
}

// -------------------------------------------------------------------------
extern "C" void kernel_launch(void* const* d_in, const int* in_sizes, int n_in,
                              void* d_out, int out_size, void* d_ws, size_t ws_size,
                              hipStream_t stream)
{
    const int*   ei     = (const int*)d_in[0];
    const float* na     = (const float*)d_in[1];
    const float* ea     = (const float*)d_in[2];
    const float* embed  = (const float*)d_in[3];
    const float* elen   = (const float*)d_in[4];
    const float* W2b0   = (const float*)d_in[5];
    const float* W2b1   = (const float*)d_in[6];
    const float* W2b2   = (const float*)d_in[7];
    const float* Wenv0  = (const float*)d_in[8];
    const float* Wlat0  = (const float*)d_in[9];
    const float* Wlat1  = (const float*)d_in[10];
    const float* Wenv1  = (const float*)d_in[11];
    const float* Wfin0  = (const float*)d_in[12];
    const float* Wfin1  = (const float*)d_in[13];
    const float* Wlin_s = (const float*)d_in[14];
    const float* Wlin_v = (const float*)d_in[15];
    const float* rp     = (const float*)d_in[16];

    float* L = (float*)d_out;   // final f32 latents (fused<4> writes once)
    const size_t E = E_EDGES;

    char* ws = (char*)d_ws;
    size_t off = 0;
    auto alloc = [&](size_t b) { void* p = ws + off; off += (b + 255) & ~(size_t)255; return p; };
    float*          cutb   = (float*)alloc(E * 4);
    unsigned short* wbuf   = (unsigned short*)alloc((size_t)1413120 * 2);
    float*          envb   = (float*)alloc((size_t)N_NODES * 128 * 4);
    unsigned short* scalb  = (unsigned short*)alloc(E * 64 * 2);
    unsigned short* feat2b = (unsigned short*)alloc(E * 128 * 2);
    unsigned short* Lb     = (unsigned short*)alloc(E * 512 * 2);
    int*            degcnt = (int*)alloc((size_t)2 * N_NODES * 4);
    int*            offs   = (int*)alloc((N_NODES + 1) * 4);
    int*            elist  = (int*)alloc(E * 4);
    unsigned short* A16b   = (unsigned short*)alloc(E * 32 * 2);
    unsigned short* R1b    = (unsigned short*)alloc(E * 128 * 2);
    unsigned short* WE1b   = (unsigned short*)alloc(E * 64 * 2);
    int* deg = degcnt;
    int* cnt = degcnt + N_NODES;

    unsigned short* W2b0t  = wbuf;
    unsigned short* W2b1t  = wbuf + 4096;
    unsigned short* W2b2t  = wbuf + 36864;
    unsigned short* Wenv0t = wbuf + 167936;
    unsigned short* Wlat0t = wbuf + 233472;
    unsigned short* Wlat1t = wbuf + 528384;
    unsigned short* Wenv1t = wbuf + 790528;
    unsigned short* Wfin0t = wbuf + 856064;
    unsigned short* Wfin1t = wbuf + 1150976;
    wtrans_all<<<5520, 256, 0, stream>>>(W2b0, W2b1, W2b2, Wenv0, Wlat0, Wlat1,
                                         Wenv1, Wfin0, Wfin1, wbuf);

    hipMemsetAsync(degcnt, 0, (size_t)2 * N_NODES * 4, stream);
    prep_kernel<<<E_EDGES / 256, 256, 0, stream>>>(ei, na, embed, elen, cutb, A16b, deg);
    scan_kernel<<<1, 1024, 0, stream>>>(deg, offs);
    fill_kernel<<<E_EDGES / 256, 256, 0, stream>>>(ei, offs, cnt, elist);
    sortseg_kernel<<<N_NODES / 4, 256, 0, stream>>>(offs, elist);

    // ---- FUSED two-body MLP: A16 -> 128 -> 256 -> 512 (*cut) -> Lb
    mlp2b<<<2500, 512, 0, stream>>>(A16b, W2b0t, W2b1t, W2b2t, cutb, Lb);

    // ---- env-embed 0: R1b = Lb @ Wenv0t  [E,128] bf16
    gemm_bf16<0><<<1250, 256, 0, stream>>>(Lb, 512, Wenv0t, 1, 128, 128, R1b);

    envgather_kernel<<<N_NODES / 2, 256, 0, stream>>>(R1b, 128, 64, ea, offs, elist, envb);
    tp0_kernel<<<E_EDGES / 8, 256, 0, stream>>>(R1b, ea, envb, ei, Wlin_s, Wlin_v, scalb, feat2b);

    // ---- FUSED latent resnet MLP: [Lb|scal](576) -> 512 silu -> 512 -> Lb
    fused_mlp<3><<<1250, 512, 0, stream>>>(Lb, scalb, Wlat0t, Wlat1t, nullptr, Lb, cutb, rp);

    // ---- env-embed 1: WE1b = Lb @ Wenv1t  [E,64] bf16 (N padded 128)
    gemm_bf16<0><<<1250, 256, 0, stream>>>(Lb, 512, Wenv1t, 1, 64, 64, WE1b);

    envgather_kernel<<<N_NODES / 2, 256, 0, stream>>>(WE1b, 64, 0, ea, offs, elist, envb);
    tp1_kernel<<<E_EDGES * 32 / 256, 256, 0, stream>>>(feat2b, envb, ei, scalb);

    // ---- FUSED final MLP: -> f32 d_out
    fused_mlp<4><<<1250, 512, 0, stream>>>(Lb, scalb, Wfin0t, Wfin1t, L, Lb, cutb, rp);
}

// Round 16
// 1586.936 us; speedup vs baseline: 3.1943x; 3.1943x over previous
//
#include <hip/hip_runtime.h>
#include <math.h>

#define E_EDGES 160000
#define N_NODES 10000

typedef __attribute__((ext_vector_type(8))) __bf16 bf16x8;
typedef __attribute__((ext_vector_type(4))) float f32x4;
typedef __attribute__((ext_vector_type(4))) unsigned int u32x4;

__device__ __forceinline__ unsigned short f2bf(float x) {
    unsigned u = __float_as_uint(x);
    u += 0x7fff + ((u >> 16) & 1);   // round-to-nearest-even
    return (unsigned short)(u >> 16);
}
__device__ __forceinline__ float bf2f(unsigned short h) {
    return __uint_as_float(((unsigned)h) << 16);
}
__device__ __forceinline__ float siluf(float v) {
    return v / (1.0f + __expf(-v));
}
__device__ __forceinline__ void gload16(const unsigned short* g, unsigned short* l) {
    __builtin_amdgcn_global_load_lds(
        (const __attribute__((address_space(1))) void*)g,
        (__attribute__((address_space(3))) void*)l, 16, 0, 0);
}

// -------------------------------------------------------------------------
// prep (+degree histogram): cutoff + 16-dim two-body rows (bf16, K pad 32)
// -------------------------------------------------------------------------
__global__ __launch_bounds__(256)
void prep_kernel(const int* __restrict__ ei, const float* __restrict__ na,
                 const float* __restrict__ embed, const float* __restrict__ elen,
                 float* __restrict__ cut, unsigned short* __restrict__ A16b,
                 int* __restrict__ deg)
{
    int e = blockIdx.x * blockDim.x + threadIdx.x;
    if (e >= E_EDGES) return;
    float r  = elen[e];
    float x  = r * (1.0f / 6.0f);
    float x2 = x * x;
    float x6 = x2 * x2 * x2;
    float c = 1.0f - 28.0f * x6 + 48.0f * x6 * x - 21.0f * x6 * x2;
    cut[e] = (x < 1.0f) ? c : 0.0f;
    int ctr = ei[e];
    int ngh = ei[E_EDGES + e];
    atomicAdd(&deg[ctr], 1);
    float4 ac = *(const float4*)(na + (size_t)ctr * 4);
    float4 an = *(const float4*)(na + (size_t)ngh * 4);
    float4 b0 = *(const float4*)(embed + (size_t)e * 8);
    float4 b1 = *(const float4*)(embed + (size_t)e * 8 + 4);
    unsigned short* o = A16b + (size_t)e * 32;
    o[0]  = f2bf(ac.x); o[1]  = f2bf(ac.y); o[2]  = f2bf(ac.z); o[3]  = f2bf(ac.w);
    o[4]  = f2bf(an.x); o[5]  = f2bf(an.y); o[6]  = f2bf(an.z); o[7]  = f2bf(an.w);
    o[8]  = f2bf(b0.x); o[9]  = f2bf(b0.y); o[10] = f2bf(b0.z); o[11] = f2bf(b0.w);
    o[12] = f2bf(b1.x); o[13] = f2bf(b1.y); o[14] = f2bf(b1.z); o[15] = f2bf(b1.w);
    #pragma unroll
    for (int i = 16; i < 32; ++i) o[i] = 0;
}

// -------------------------------------------------------------------------
// all 9 weight transposes in one grid; scale folded. Bt[n*Kpad+k]=W[k*N+n]*sc
// -------------------------------------------------------------------------
__global__ __launch_bounds__(256)
void wtrans_all(const float* __restrict__ w0, const float* __restrict__ w1,
                const float* __restrict__ w2, const float* __restrict__ w3,
                const float* __restrict__ w4, const float* __restrict__ w5,
                const float* __restrict__ w6, const float* __restrict__ w7,
                const float* __restrict__ w8, unsigned short* __restrict__ wbuf)
{
    int blk = blockIdx.x;
    const float* W; int K, N, Kpad, Npad; size_t dbase; int lstart; float sc;
    const float s16  = 0.25f;
    const float s128 = 0.088388347648318447f;
    const float s256 = 0.0625f;
    const float s512 = 0.044194173824159223f;
    const float s576 = 0.041666666666666664f;
    if      (blk <   16) { W=w0; K=16;  N=128; Kpad=32;  Npad=128; dbase=0;       lstart=0;    sc=s16;  }
    else if (blk <  144) { W=w1; K=128; N=256; Kpad=128; Npad=256; dbase=4096;    lstart=16;   sc=s128; }
    else if (blk <  656) { W=w2; K=256; N=512; Kpad=256; Npad=512; dbase=36864;   lstart=144;  sc=s256; }
    else if (blk <  912) { W=w3; K=512; N=128; Kpad=512; Npad=128; dbase=167936;  lstart=656;  sc=s512; }
    else if (blk < 2064) { W=w4; K=576; N=512; Kpad=576; Npad=512; dbase=233472;  lstart=912;  sc=s576; }
    else if (blk < 3088) { W=w5; K=512; N=512; Kpad=512; Npad=512; dbase=528384;  lstart=2064; sc=s512; }
    else if (blk < 3344) { W=w6; K=512; N=64;  Kpad=512; Npad=128; dbase=790528;  lstart=3088; sc=s512; }
    else if (blk < 4496) { W=w7; K=576; N=512; Kpad=576; Npad=512; dbase=856064;  lstart=3344; sc=s576; }
    else                 { W=w8; K=512; N=512; Kpad=512; Npad=512; dbase=1150976; lstart=4496; sc=s512; }
    int local = (blk - lstart) * 256 + threadIdx.x;
    int n = local % Npad, k = local / Npad;
    if (k >= Kpad) return;
    float v = (k < K && n < N) ? W[(size_t)k * N + n] * sc : 0.0f;
    wbuf[dbase + (size_t)n * Kpad + k] = f2bf(v);
}

// -------------------------------------------------------------------------
// CSR: scan, fill, wave-bitonic per-segment sort (deterministic)
// -------------------------------------------------------------------------
__global__ __launch_bounds__(1024)
void scan_kernel(const int* __restrict__ deg, int* __restrict__ offs)
{
    __shared__ int part[1024];
    int t = threadIdx.x;
    int base = t * 10;
    int loc[10];
    int s = 0;
    #pragma unroll
    for (int i = 0; i < 10; ++i) {
        int idx = base + i;
        int d = (idx < N_NODES) ? deg[idx] : 0;
        loc[i] = s; s += d;
    }
    part[t] = s;
    __syncthreads();
    for (int o = 1; o < 1024; o <<= 1) {
        int v = (t >= o) ? part[t - o] : 0;
        __syncthreads();
        part[t] += v;
        __syncthreads();
    }
    int excl = (t > 0) ? part[t - 1] : 0;
    #pragma unroll
    for (int i = 0; i < 10; ++i) {
        int idx = base + i;
        if (idx < N_NODES) offs[idx] = excl + loc[i];
    }
    if (t == 1023) offs[N_NODES] = part[1023];
}

__global__ __launch_bounds__(256)
void fill_kernel(const int* __restrict__ ei, const int* __restrict__ offs,
                 int* __restrict__ cnt, int* __restrict__ elist)
{
    int e = blockIdx.x * blockDim.x + threadIdx.x;
    if (e >= E_EDGES) return;
    int c = ei[e];
    int pos = offs[c] + atomicAdd(&cnt[c], 1);
    elist[pos] = e;
}

__global__ __launch_bounds__(256)
void sortseg_kernel(const int* __restrict__ offs, int* __restrict__ elist)
{
    int node = blockIdx.x * 4 + (threadIdx.x >> 6);
    int l = threadIdx.x & 63;
    if (node >= N_NODES) return;
    int b = offs[node], en = offs[node + 1];
    int deg = en - b;
    if (deg <= 1) return;
    if (deg <= 64) {
        int v = (l < deg) ? elist[b + l] : 0x7fffffff;
        #pragma unroll
        for (int k = 2; k <= 64; k <<= 1) {
            #pragma unroll
            for (int j = k >> 1; j > 0; j >>= 1) {
                int o = __shfl_xor(v, j);
                bool dirUp = ((l & k) == 0);
                bool lower = ((l & j) == 0);
                int mn = v < o ? v : o;
                int mx = v < o ? o : v;
                v = (dirUp == lower) ? mn : mx;
            }
        }
        if (l < deg) elist[b + l] = v;
    } else if (l == 0) {
        for (int i = b + 1; i < en; ++i) {
            int v = elist[i];
            int j = i - 1;
            while (j >= b && elist[j] > v) { elist[j + 1] = elist[j]; --j; }
            elist[j + 1] = v;
        }
    }
}

// -------------------------------------------------------------------------
// env gather-sum (plain stores)
// -------------------------------------------------------------------------
__global__ __launch_bounds__(256)
void envgather_kernel(const unsigned short* __restrict__ Wb, int wstride, int woff,
                      const float* __restrict__ ea, const int* __restrict__ offs,
                      const int* __restrict__ elist, float* __restrict__ env)
{
    int n = blockIdx.x * 2 + (threadIdx.x >> 7);
    int t = threadIdx.x & 127;
    if (n >= N_NODES) return;
    int u = t >> 2, comp = t & 3;
    int widx = woff + u * 2 + (comp ? 1 : 0);
    int beg = offs[n], end = offs[n + 1];
    float acc = 0.0f;
    for (int i = beg; i < end; ++i) {
        int e = elist[i];
        float w = bf2f(Wb[(size_t)e * wstride + widx]);
        float a = ea[(size_t)e * 4 + comp];
        acc += a * w;
    }
    env[(size_t)n * 128 + t] = acc * 0.25f;   // 1/sqrt(16)
}

// -------------------------------------------------------------------------
// bf16 MFMA GEMM (round-14): 128x128 tile, BK=32, 4 waves, 3 LDS pairs,
// counted-vmcnt depth-2 pipeline, ONE barrier/iter, XOR swizzle, unpinned.
// -------------------------------------------------------------------------
template<int EPIL>
__global__ __launch_bounds__(256)
void gemm_bf16(const unsigned short* __restrict__ A1,
               int K, const unsigned short* __restrict__ Bt,
               int nx, int ldc, int Nstore,
               unsigned short* __restrict__ Cb)
{
    __shared__ __align__(16) unsigned short SB[3][2][128 * 32];
    const int tid  = threadIdx.x;
    const int lane = tid & 63;
    const int wid  = tid >> 6;
    const int wr   = wid >> 1, wc = wid & 1;
    const int nwg = gridDim.x;
    const int fid = blockIdx.x;
    const int q = nwg >> 3, r = nwg & 7;
    const int xcd = fid & 7, j = fid >> 3;
    const int L = ((xcd < r) ? xcd * (q + 1) : r * (q + 1) + (xcd - r) * q) + j;
    const int bn = (L % nx) * 128;
    const int bm = (L / nx) * 128;

    const int l15 = lane & 15;
    const int l4r = lane >> 2;
    const int sk8 = (((lane & 3) ^ ((lane >> 3) & 3)) << 3);
    const int rk8 = ((((lane >> 4) ^ ((l15 >> 1) & 3)) & 3) << 3);
    const int T   = K >> 5;

    f32x4 acc[4][4] = {};

    auto stage = [&](int t, int b) {
        int k0 = t << 5;
        #pragma unroll
        for (int i = 0; i < 2; ++i) {
            int ch  = (wid << 1) + i;
            int row = (ch << 4) + l4r;
            gload16(A1 + (size_t)(bm + row) * K + k0 + sk8, &SB[b][0][ch << 9]);
            gload16(Bt + (size_t)(bn + row) * K + k0 + sk8, &SB[b][1][ch << 9]);
        }
    };

    stage(0, 0);
    if (T >= 2) stage(1, 1);

    for (int t = 0; t < T; ++t) {
        if (t < T - 1) asm volatile("s_waitcnt vmcnt(4)" ::: "memory");
        else           asm volatile("s_waitcnt vmcnt(0)" ::: "memory");
        __builtin_amdgcn_s_barrier();
        __builtin_amdgcn_sched_barrier(0);

        if (t + 2 < T) stage(t + 2, (t + 2) % 3);

        const unsigned short* As = &SB[t % 3][0][0];
        const unsigned short* Bs = &SB[t % 3][1][0];
        bf16x8 af[4], bfr[4];
        #pragma unroll
        for (int m = 0; m < 4; ++m)
            af[m] = __builtin_bit_cast(bf16x8, *(const u32x4*)&As[(wr * 64 + m * 16 + l15) * 32 + rk8]);
        #pragma unroll
        for (int n = 0; n < 4; ++n)
            bfr[n] = __builtin_bit_cast(bf16x8, *(const u32x4*)&Bs[(wc * 64 + n * 16 + l15) * 32 + rk8]);

        __builtin_amdgcn_s_setprio(1);
        #pragma unroll
        for (int m = 0; m < 4; ++m)
            #pragma unroll
            for (int n = 0; n < 4; ++n)
                acc[m][n] = __builtin_amdgcn_mfma_f32_16x16x32_bf16(af[m], bfr[n], acc[m][n], 0, 0, 0);
        __builtin_amdgcn_s_setprio(0);
    }

    #pragma unroll
    for (int m = 0; m < 4; ++m) {
        int rbase = bm + wr * 64 + m * 16 + ((lane >> 4) << 2);
        #pragma unroll
        for (int n = 0; n < 4; ++n) {
            int col = bn + wc * 64 + n * 16 + l15;
            if (col < Nstore) {
                #pragma unroll
                for (int rr = 0; rr < 4; ++rr) {
                    int row = rbase + rr;
                    Cb[(size_t)row * ldc + col] = f2bf(acc[m][n][rr]);
                }
            }
        }
    }
}

// -------------------------------------------------------------------------
// FUSED two-body MLP (round-10 proven): Lb = cut * (silu(silu(A16@W0)@W1)@W2)
// -------------------------------------------------------------------------
__global__ __launch_bounds__(512)
void mlp2b(const unsigned short* __restrict__ A16b,
           const unsigned short* __restrict__ W0t,   // [128][32]
           const unsigned short* __restrict__ W1t,   // [256][128]
           const unsigned short* __restrict__ W2t,   // [512][256]
           const float* __restrict__ cut, unsigned short* __restrict__ Lb)
{
    __shared__ __align__(16) unsigned short SA[64 * 32];
    __shared__ __align__(16) unsigned short H1[64 * 128];
    __shared__ __align__(16) unsigned short H2[64 * 256];
    const int tid  = threadIdx.x;
    const int lane = tid & 63;
    const int wid  = tid >> 6;
    const int l15  = lane & 15;
    const int l4r  = lane >> 2;
    const int lk8  = (lane >> 4) << 3;
    const int sk8  = (((lane & 3) ^ ((lane >> 3) & 3)) << 3);
    const int rk8  = ((((lane >> 4) ^ ((l15 >> 1) & 3)) & 3) << 3);
    const int bm   = blockIdx.x * 64;
    const int hrow4 = (lane >> 4) << 2;

    if (wid < 4) {
        int row = (wid << 4) + l4r;
        gload16(A16b + (size_t)(bm + row) * 32 + sk8, &SA[wid << 9]);
    }
    asm volatile("s_waitcnt vmcnt(0)" ::: "memory");
    __builtin_amdgcn_s_barrier();
    __builtin_amdgcn_sched_barrier(0);

    // ---- stage A: H1[64][128] = silu(A @ W0^T)
    {
        int hc = wid * 16 + l15;
        bf16x8 wf = __builtin_bit_cast(bf16x8, *(const u32x4*)(W0t + (size_t)hc * 32 + lk8));
        #pragma unroll
        for (int mi = 0; mi < 4; ++mi) {
            bf16x8 af = __builtin_bit_cast(bf16x8, *(const u32x4*)&SA[(mi * 16 + l15) * 32 + rk8]);
            f32x4 a = {};
            a = __builtin_amdgcn_mfma_f32_16x16x32_bf16(af, wf, a, 0, 0, 0);
            #pragma unroll
            for (int rr = 0; rr < 4; ++rr) {
                int er = mi * 16 + hrow4 + rr;
                H1[er * 128 + (((hc >> 3) ^ (er & 7)) << 3) + (hc & 7)] = f2bf(siluf(a[rr]));
            }
        }
    }
    asm volatile("s_waitcnt lgkmcnt(0)" ::: "memory");
    __builtin_amdgcn_s_barrier();
    __builtin_amdgcn_sched_barrier(0);

    // ---- stage B: H2[64][256] = silu(H1 @ W1^T)
    {
        f32x4 acc[4][2] = {};
        #pragma unroll
        for (int kt = 0; kt < 4; ++kt) {
            bf16x8 hf[4], wf[2];
            #pragma unroll
            for (int fa = 0; fa < 4; ++fa) {
                int er = fa * 16 + l15;
                int slotp = (kt * 4 + (lane >> 4)) ^ (er & 7);
                hf[fa] = __builtin_bit_cast(bf16x8, *(const u32x4*)&H1[er * 128 + slotp * 8]);
            }
            #pragma unroll
            for (int fb = 0; fb < 2; ++fb) {
                int hc = wid * 32 + fb * 16 + l15;
                wf[fb] = __builtin_bit_cast(bf16x8, *(const u32x4*)(W1t + (size_t)hc * 128 + kt * 32 + lk8));
            }
            #pragma unroll
            for (int fa = 0; fa < 4; ++fa)
                #pragma unroll
                for (int fb = 0; fb < 2; ++fb)
                    acc[fa][fb] = __builtin_amdgcn_mfma_f32_16x16x32_bf16(hf[fa], wf[fb], acc[fa][fb], 0, 0, 0);
        }
        asm volatile("s_waitcnt lgkmcnt(0)" ::: "memory");
        __builtin_amdgcn_s_barrier();
        #pragma unroll
        for (int fa = 0; fa < 4; ++fa)
            #pragma unroll
            for (int fb = 0; fb < 2; ++fb)
                #pragma unroll
                for (int rr = 0; rr < 4; ++rr) {
                    int er = fa * 16 + hrow4 + rr;
                    int hc = wid * 32 + fb * 16 + l15;
                    H2[er * 256 + (((hc >> 3) ^ (er & 7)) << 3) + (hc & 7)] = f2bf(siluf(acc[fa][fb][rr]));
                }
    }
    asm volatile("s_waitcnt lgkmcnt(0)" ::: "memory");
    __builtin_amdgcn_s_barrier();
    __builtin_amdgcn_sched_barrier(0);

    // ---- stage C: O[64][512] = cut * (H2 @ W2^T)
    f32x4 acc[4][4] = {};
    #pragma unroll 1
    for (int kt = 0; kt < 8; ++kt) {
        bf16x8 hf[4], wf[4];
        #pragma unroll
        for (int fa = 0; fa < 4; ++fa) {
            int er = fa * 16 + l15;
            int slotp = (kt * 4 + (lane >> 4)) ^ (er & 7);
            hf[fa] = __builtin_bit_cast(bf16x8, *(const u32x4*)&H2[er * 256 + slotp * 8]);
        }
        #pragma unroll
        for (int fb = 0; fb < 4; ++fb) {
            int oc = wid * 64 + fb * 16 + l15;
            wf[fb] = __builtin_bit_cast(bf16x8, *(const u32x4*)(W2t + (size_t)oc * 256 + kt * 32 + lk8));
        }
        __builtin_amdgcn_s_setprio(1);
        #pragma unroll
        for (int fa = 0; fa < 4; ++fa)
            #pragma unroll
            for (int fb = 0; fb < 4; ++fb)
                acc[fa][fb] = __builtin_amdgcn_mfma_f32_16x16x32_bf16(hf[fa], wf[fb], acc[fa][fb], 0, 0, 0);
        __builtin_amdgcn_s_setprio(0);
    }
    #pragma unroll
    for (int fa = 0; fa < 4; ++fa) {
        int rbase = bm + fa * 16 + hrow4;
        #pragma unroll
        for (int fb = 0; fb < 4; ++fb) {
            int col = wid * 64 + fb * 16 + l15;
            #pragma unroll
            for (int rr = 0; rr < 4; ++rr) {
                int row = rbase + rr;
                Lb[(size_t)row * 512 + col] = f2bf(acc[fa][fb][rr] * cut[row]);
            }
        }
    }
}

// -------------------------------------------------------------------------
// FUSED two-layer MLP, 64 rows / 4 waves / 72KB LDS -> 2 blocks/CU.
// Wave owns 128 output cols (8 frags) => 32 MFMA/iter/wave preserved.
// acc1 dies at silu-write before acc2 is created (no lifetime overlap).
// EPIL2: 3 = resnet1 -> Lb bf16 (in-place), 4 = resnet2 -> L f32
// -------------------------------------------------------------------------
template<int EPIL2>
__global__ __launch_bounds__(256)
void fused_mlp(const unsigned short* __restrict__ A1,   // Lb [E,512]
               const unsigned short* __restrict__ A2,   // scalb [E,64]
               const unsigned short* __restrict__ W1t,  // [512][576]
               const unsigned short* __restrict__ W2t,  // [512][512]
               float* __restrict__ Cf, unsigned short* __restrict__ Cb,
               const float* __restrict__ cut, const float* __restrict__ rp)
{
    __shared__ __align__(16) unsigned short Hl[64 * 512];   // 64 KB swizzled
    __shared__ __align__(16) unsigned short SA[2][64 * 32]; // 2 x 4 KB A staging
    const int tid  = threadIdx.x;
    const int lane = tid & 63;
    const int wid  = tid >> 6;            // 0..3
    const int l15  = lane & 15;
    const int l4r  = lane >> 2;
    const int lk8  = (lane >> 4) << 3;    // k sub-offset (shorts)
    const int sk8  = (((lane & 3) ^ ((lane >> 3) & 3)) << 3);
    const int rk8  = ((((lane >> 4) ^ ((l15 >> 1) & 3)) & 3) << 3);
    const int bm   = blockIdx.x * 64;
    const int col0 = wid * 128;           // wave's 128-col strip
    const int hrow4 = (lane >> 4) << 2;

    auto stageA = [&](int t, int b) {
        int k0 = t << 5;
        int row = (wid << 4) + l4r;       // 4 waves cover rows 0..63
        const unsigned short* gp;
        if (k0 < 512) gp = A1 + (size_t)(bm + row) * 512 + k0 + sk8;
        else          gp = A2 + (size_t)(bm + row) * 64 + (k0 - 512) + sk8;
        gload16(gp, &SA[b][wid << 9]);
    };

    f32x4 acc1[4][8] = {};
    stageA(0, 0);

    // ---- stage 1: acc1 = A @ W1^T  (depth-1 SA pipeline, W1 from L2)
    for (int t = 0; t < 18; ++t) {
        asm volatile("s_waitcnt vmcnt(0)" ::: "memory");
        __builtin_amdgcn_s_barrier();
        __builtin_amdgcn_sched_barrier(0);

        if (t + 1 < 18) stageA(t + 1, (t + 1) & 1);

        const unsigned short* As = &SA[t & 1][0];
        int k0 = t << 5;
        bf16x8 af[4], wf[8];
        #pragma unroll
        for (int mi = 0; mi < 4; ++mi)
            af[mi] = __builtin_bit_cast(bf16x8, *(const u32x4*)&As[(mi * 16 + l15) * 32 + rk8]);
        #pragma unroll
        for (int ni = 0; ni < 8; ++ni) {
            int hc = col0 + ni * 16 + l15;
            wf[ni] = __builtin_bit_cast(bf16x8, *(const u32x4*)(W1t + (size_t)hc * 576 + k0 + lk8));
        }

        __builtin_amdgcn_s_setprio(1);
        #pragma unroll
        for (int mi = 0; mi < 4; ++mi)
            #pragma unroll
            for (int ni = 0; ni < 8; ++ni)
                acc1[mi][ni] = __builtin_amdgcn_mfma_f32_16x16x32_bf16(af[mi], wf[ni], acc1[mi][ni], 0, 0, 0);
        __builtin_amdgcn_s_setprio(0);
    }

    // --- silu + write H to swizzled LDS (acc1 dies here)
    #pragma unroll
    for (int mi = 0; mi < 4; ++mi)
        #pragma unroll
        for (int ni = 0; ni < 8; ++ni)
            #pragma unroll
            for (int rr = 0; rr < 4; ++rr) {
                int er = mi * 16 + hrow4 + rr;
                int hc = col0 + ni * 16 + l15;
                Hl[er * 512 + (((hc >> 3) ^ (er & 7)) << 3) + (hc & 7)] = f2bf(siluf(acc1[mi][ni][rr]));
            }
    asm volatile("s_waitcnt lgkmcnt(0)" ::: "memory");
    __builtin_amdgcn_s_barrier();
    __builtin_amdgcn_sched_barrier(0);

    // --- stage 2: barrier-free; H frags from LDS, W2 frags from L2
    f32x4 acc2[4][8] = {};
    #pragma unroll 1
    for (int kt = 0; kt < 16; ++kt) {
        bf16x8 hf[4], w2f[8];
        #pragma unroll
        for (int fa = 0; fa < 4; ++fa) {
            int er = fa * 16 + l15;
            int slotp = (kt * 4 + (lane >> 4)) ^ (er & 7);
            hf[fa] = __builtin_bit_cast(bf16x8, *(const u32x4*)&Hl[er * 512 + slotp * 8]);
        }
        #pragma unroll
        for (int fb = 0; fb < 8; ++fb) {
            int oc = col0 + fb * 16 + l15;
            w2f[fb] = __builtin_bit_cast(bf16x8, *(const u32x4*)(W2t + (size_t)oc * 512 + kt * 32 + lk8));
        }
        __builtin_amdgcn_s_setprio(1);
        #pragma unroll
        for (int fa = 0; fa < 4; ++fa)
            #pragma unroll
            for (int fb = 0; fb < 8; ++fb)
                acc2[fa][fb] = __builtin_amdgcn_mfma_f32_16x16x32_bf16(hf[fa], w2f[fb], acc2[fa][fb], 0, 0, 0);
        __builtin_amdgcn_s_setprio(0);
    }

    // --- resnet epilogue (coalesced)
    float c0 = __expf(rp[0]), c1 = __expf(rp[1]), c2 = __expf(rp[2]);
    #pragma unroll
    for (int fa = 0; fa < 4; ++fa) {
        int rbase = bm + fa * 16 + hrow4;
        #pragma unroll
        for (int fb = 0; fb < 8; ++fb) {
            int col = col0 + fb * 16 + l15;
            #pragma unroll
            for (int rr = 0; rr < 4; ++rr) {
                int row = rbase + rr;
                float v = acc2[fa][fb][rr];
                size_t off2 = (size_t)row * 512 + col;
                if (EPIL2 == 3) {
                    float old = bf2f(Cb[off2]);
                    v = (c0 * old + c1 * v * cut[row]) * rsqrtf(c0 * c0 + c1 * c1);
                    Cb[off2] = f2bf(v);
                } else {
                    float old = bf2f(Cb[off2]);
                    float n2 = c0 * c0 + c1 * c1;
                    v = (sqrtf(n2) * old + c2 * v * cut[row]) * rsqrtf(n2 + c2 * c2);
                    Cf[off2] = v;
                }
            }
        }
    }
}

// -------------------------------------------------------------------------
// TP0 + e3nn Linear; Ws/Wv staged in LDS with alpha folded
// -------------------------------------------------------------------------
__global__ __launch_bounds__(256)
void tp0_kernel(const unsigned short* __restrict__ W0b, const float* __restrict__ ea,
                const float* __restrict__ env, const int* __restrict__ ei,
                const float* __restrict__ Ws, const float* __restrict__ Wv,
                unsigned short* __restrict__ scalb, unsigned short* __restrict__ feat2b)
{
    __shared__ float sc[8][64];
    __shared__ float xv[8][64][3];
    __shared__ float Wsl[2048];
    __shared__ float Wvl[2048];
    int tid = threadIdx.x;
    const float alpha = 0.125f;  // 1/sqrt(2U)
    #pragma unroll
    for (int i = 0; i < 8; ++i) {
        Wsl[tid + i * 256] = Ws[tid + i * 256] * alpha;
        Wvl[tid + i * 256] = Wv[tid + i * 256] * alpha;
    }
    int le = tid >> 5;
    int u  = tid & 31;
    int e  = blockIdx.x * 8 + le;
    int c  = ei[e];
    float4 a = *(const float4*)(ea + (size_t)e * 4);
    const float* ep = env + (size_t)c * 128 + u * 4;
    float e0 = ep[0], e1 = ep[1], e2 = ep[2], e3 = ep[3];
    float wf0 = bf2f(W0b[(size_t)e * 128 + u * 2]);
    float wf1 = bf2f(W0b[(size_t)e * 128 + u * 2 + 1]);
    float f0 = a.x * wf0;
    float f1 = a.y * wf1, f2 = a.z * wf1, f3 = a.w * wf1;
    const float rs3 = 0.57735026918962576f;
    float t0 = f0 * e0;
    float t1 = (f1 * e1 + f2 * e2 + f3 * e3) * rs3;
    scalb[(size_t)e * 64 + u]      = f2bf(t0);
    scalb[(size_t)e * 64 + 32 + u] = f2bf(t1);
    sc[le][u]      = t0;
    sc[le][32 + u] = t1;
    xv[le][u][0] = f0 * e1; xv[le][u][1] = f0 * e2; xv[le][u][2] = f0 * e3;
    xv[le][32 + u][0] = f1 * e0; xv[le][32 + u][1] = f2 * e0; xv[le][32 + u][2] = f3 * e0;
    __syncthreads();
    float ys = 0.0f, yv0 = 0.0f, yv1 = 0.0f, yv2 = 0.0f;
    #pragma unroll 8
    for (int k = 0; k < 64; ++k) {
        float ws = Wsl[k * 32 + u];
        float wv = Wvl[k * 32 + u];
        ys  = fmaf(sc[le][k], ws, ys);
        yv0 = fmaf(xv[le][k][0], wv, yv0);
        yv1 = fmaf(xv[le][k][1], wv, yv1);
        yv2 = fmaf(xv[le][k][2], wv, yv2);
    }
    ushort4 ov;
    ov.x = f2bf(ys);
    ov.y = f2bf(yv0);
    ov.z = f2bf(yv1);
    ov.w = f2bf(yv2);
    *(ushort4*)(feat2b + (size_t)e * 128 + u * 4) = ov;
}

// -------------------------------------------------------------------------
// TP1 (scalar outputs only) -> scalars2 bf16 [E,64]
// -------------------------------------------------------------------------
__global__ __launch_bounds__(256)
void tp1_kernel(const unsigned short* __restrict__ feat2b, const float* __restrict__ env,
                const int* __restrict__ ei, unsigned short* __restrict__ scalb)
{
    int idx = blockIdx.x * blockDim.x + threadIdx.x;
    if (idx >= E_EDGES * 32) return;
    int e = idx >> 5, u = idx & 31;
    int c = ei[e];
    const float* ep = env + (size_t)c * 128 + u * 4;
    ushort4 f4 = *(const ushort4*)(feat2b + (size_t)e * 128 + u * 4);
    float fx = bf2f(f4.x), fy = bf2f(f4.y), fz = bf2f(f4.z), fw = bf2f(f4.w);
    const float rs3 = 0.57735026918962576f;
    float t0 = fx * ep[0];
    float t1 = (fy * ep[1] + fz * ep[2] + fw * ep[3]) * rs3;
    scalb[(size_t)e * 64 + u]      = f2bf(t0);
    scalb[(size_t)e * 64 + 32 + u] = f2bf(t1);
}

// -------------------------------------------------------------------------
extern "C" void kernel_launch(void* const* d_in, const int* in_sizes, int n_in,
                              void* d_out, int out_size, void* d_ws, size_t ws_size,
                              hipStream_t stream)
{
    const int*   ei     = (const int*)d_in[0];
    const float* na     = (const float*)d_in[1];
    const float* ea     = (const float*)d_in[2];
    const float* embed  = (const float*)d_in[3];
    const float* elen   = (const float*)d_in[4];
    const float* W2b0   = (const float*)d_in[5];
    const float* W2b1   = (const float*)d_in[6];
    const float* W2b2   = (const float*)d_in[7];
    const float* Wenv0  = (const float*)d_in[8];
    const float* Wlat0  = (const float*)d_in[9];
    const float* Wlat1  = (const float*)d_in[10];
    const float* Wenv1  = (const float*)d_in[11];
    const float* Wfin0  = (const float*)d_in[12];
    const float* Wfin1  = (const float*)d_in[13];
    const float* Wlin_s = (const float*)d_in[14];
    const float* Wlin_v = (const float*)d_in[15];
    const float* rp     = (const float*)d_in[16];

    float* L = (float*)d_out;   // final f32 latents (fused<4> writes once)
    const size_t E = E_EDGES;

    char* ws = (char*)d_ws;
    size_t off = 0;
    auto alloc = [&](size_t b) { void* p = ws + off; off += (b + 255) & ~(size_t)255; return p; };
    float*          cutb   = (float*)alloc(E * 4);
    unsigned short* wbuf   = (unsigned short*)alloc((size_t)1413120 * 2);
    float*          envb   = (float*)alloc((size_t)N_NODES * 128 * 4);
    unsigned short* scalb  = (unsigned short*)alloc(E * 64 * 2);
    unsigned short* feat2b = (unsigned short*)alloc(E * 128 * 2);
    unsigned short* Lb     = (unsigned short*)alloc(E * 512 * 2);
    int*            degcnt = (int*)alloc((size_t)2 * N_NODES * 4);
    int*            offs   = (int*)alloc((N_NODES + 1) * 4);
    int*            elist  = (int*)alloc(E * 4);
    unsigned short* A16b   = (unsigned short*)alloc(E * 32 * 2);
    unsigned short* R1b    = (unsigned short*)alloc(E * 128 * 2);
    unsigned short* WE1b   = (unsigned short*)alloc(E * 64 * 2);
    int* deg = degcnt;
    int* cnt = degcnt + N_NODES;

    unsigned short* W2b0t  = wbuf;
    unsigned short* W2b1t  = wbuf + 4096;
    unsigned short* W2b2t  = wbuf + 36864;
    unsigned short* Wenv0t = wbuf + 167936;
    unsigned short* Wlat0t = wbuf + 233472;
    unsigned short* Wlat1t = wbuf + 528384;
    unsigned short* Wenv1t = wbuf + 790528;
    unsigned short* Wfin0t = wbuf + 856064;
    unsigned short* Wfin1t = wbuf + 1150976;
    wtrans_all<<<5520, 256, 0, stream>>>(W2b0, W2b1, W2b2, Wenv0, Wlat0, Wlat1,
                                         Wenv1, Wfin0, Wfin1, wbuf);

    hipMemsetAsync(degcnt, 0, (size_t)2 * N_NODES * 4, stream);
    prep_kernel<<<E_EDGES / 256, 256, 0, stream>>>(ei, na, embed, elen, cutb, A16b, deg);
    scan_kernel<<<1, 1024, 0, stream>>>(deg, offs);
    fill_kernel<<<E_EDGES / 256, 256, 0, stream>>>(ei, offs, cnt, elist);
    sortseg_kernel<<<N_NODES / 4, 256, 0, stream>>>(offs, elist);

    // ---- FUSED two-body MLP: A16 -> 128 -> 256 -> 512 (*cut) -> Lb
    mlp2b<<<2500, 512, 0, stream>>>(A16b, W2b0t, W2b1t, W2b2t, cutb, Lb);

    // ---- env-embed 0: R1b = Lb @ Wenv0t  [E,128] bf16
    gemm_bf16<0><<<1250, 256, 0, stream>>>(Lb, 512, Wenv0t, 1, 128, 128, R1b);

    envgather_kernel<<<N_NODES / 2, 256, 0, stream>>>(R1b, 128, 64, ea, offs, elist, envb);
    tp0_kernel<<<E_EDGES / 8, 256, 0, stream>>>(R1b, ea, envb, ei, Wlin_s, Wlin_v, scalb, feat2b);

    // ---- FUSED latent resnet MLP: [Lb|scal](576) -> 512 silu -> 512 -> Lb
    fused_mlp<3><<<2500, 256, 0, stream>>>(Lb, scalb, Wlat0t, Wlat1t, nullptr, Lb, cutb, rp);

    // ---- env-embed 1: WE1b = Lb @ Wenv1t  [E,64] bf16 (N padded 128)
    gemm_bf16<0><<<1250, 256, 0, stream>>>(Lb, 512, Wenv1t, 1, 64, 64, WE1b);

    envgather_kernel<<<N_NODES / 2, 256, 0, stream>>>(WE1b, 64, 0, ea, offs, elist, envb);
    tp1_kernel<<<E_EDGES * 32 / 256, 256, 0, stream>>>(feat2b, envb, ei, scalb);

    // ---- FUSED final MLP: -> f32 d_out
    fused_mlp<4><<<2500, 256, 0, stream>>>(Lb, scalb, Wfin0t, Wfin1t, L, Lb, cutb, rp);
}

// Round 17
// 1203.476 us; speedup vs baseline: 4.2121x; 1.3186x over previous
//
#include <hip/hip_runtime.h>
#include <math.h>

#define E_EDGES 160000
#define N_NODES 10000

typedef __attribute__((ext_vector_type(8))) __bf16 bf16x8;
typedef __attribute__((ext_vector_type(4))) float f32x4;
typedef __attribute__((ext_vector_type(4))) unsigned int u32x4;

__device__ __forceinline__ unsigned short f2bf(float x) {
    unsigned u = __float_as_uint(x);
    u += 0x7fff + ((u >> 16) & 1);   // round-to-nearest-even
    return (unsigned short)(u >> 16);
}
__device__ __forceinline__ float bf2f(unsigned short h) {
    return __uint_as_float(((unsigned)h) << 16);
}
__device__ __forceinline__ float siluf(float v) {
    return v / (1.0f + __expf(-v));
}
__device__ __forceinline__ void gload16(const unsigned short* g, unsigned short* l) {
    __builtin_amdgcn_global_load_lds(
        (const __attribute__((address_space(1))) void*)g,
        (__attribute__((address_space(3))) void*)l, 16, 0, 0);
}

// -------------------------------------------------------------------------
// prep (+degree histogram): cutoff + 16-dim two-body rows (bf16, K pad 32)
// -------------------------------------------------------------------------
__global__ __launch_bounds__(256)
void prep_kernel(const int* __restrict__ ei, const float* __restrict__ na,
                 const float* __restrict__ embed, const float* __restrict__ elen,
                 float* __restrict__ cut, unsigned short* __restrict__ A16b,
                 int* __restrict__ deg)
{
    int e = blockIdx.x * blockDim.x + threadIdx.x;
    if (e >= E_EDGES) return;
    float r  = elen[e];
    float x  = r * (1.0f / 6.0f);
    float x2 = x * x;
    float x6 = x2 * x2 * x2;
    float c = 1.0f - 28.0f * x6 + 48.0f * x6 * x - 21.0f * x6 * x2;
    cut[e] = (x < 1.0f) ? c : 0.0f;
    int ctr = ei[e];
    int ngh = ei[E_EDGES + e];
    atomicAdd(&deg[ctr], 1);
    float4 ac = *(const float4*)(na + (size_t)ctr * 4);
    float4 an = *(const float4*)(na + (size_t)ngh * 4);
    float4 b0 = *(const float4*)(embed + (size_t)e * 8);
    float4 b1 = *(const float4*)(embed + (size_t)e * 8 + 4);
    unsigned short* o = A16b + (size_t)e * 32;
    o[0]  = f2bf(ac.x); o[1]  = f2bf(ac.y); o[2]  = f2bf(ac.z); o[3]  = f2bf(ac.w);
    o[4]  = f2bf(an.x); o[5]  = f2bf(an.y); o[6]  = f2bf(an.z); o[7]  = f2bf(an.w);
    o[8]  = f2bf(b0.x); o[9]  = f2bf(b0.y); o[10] = f2bf(b0.z); o[11] = f2bf(b0.w);
    o[12] = f2bf(b1.x); o[13] = f2bf(b1.y); o[14] = f2bf(b1.z); o[15] = f2bf(b1.w);
    #pragma unroll
    for (int i = 16; i < 32; ++i) o[i] = 0;
}

// -------------------------------------------------------------------------
// all 9 weight transposes in one grid; scale folded. Bt[n*Kpad+k]=W[k*N+n]*sc
// -------------------------------------------------------------------------
__global__ __launch_bounds__(256)
void wtrans_all(const float* __restrict__ w0, const float* __restrict__ w1,
                const float* __restrict__ w2, const float* __restrict__ w3,
                const float* __restrict__ w4, const float* __restrict__ w5,
                const float* __restrict__ w6, const float* __restrict__ w7,
                const float* __restrict__ w8, unsigned short* __restrict__ wbuf)
{
    int blk = blockIdx.x;
    const float* W; int K, N, Kpad, Npad; size_t dbase; int lstart; float sc;
    const float s16  = 0.25f;
    const float s128 = 0.088388347648318447f;
    const float s256 = 0.0625f;
    const float s512 = 0.044194173824159223f;
    const float s576 = 0.041666666666666664f;
    if      (blk <   16) { W=w0; K=16;  N=128; Kpad=32;  Npad=128; dbase=0;       lstart=0;    sc=s16;  }
    else if (blk <  144) { W=w1; K=128; N=256; Kpad=128; Npad=256; dbase=4096;    lstart=16;   sc=s128; }
    else if (blk <  656) { W=w2; K=256; N=512; Kpad=256; Npad=512; dbase=36864;   lstart=144;  sc=s256; }
    else if (blk <  912) { W=w3; K=512; N=128; Kpad=512; Npad=128; dbase=167936;  lstart=656;  sc=s512; }
    else if (blk < 2064) { W=w4; K=576; N=512; Kpad=576; Npad=512; dbase=233472;  lstart=912;  sc=s576; }
    else if (blk < 3088) { W=w5; K=512; N=512; Kpad=512; Npad=512; dbase=528384;  lstart=2064; sc=s512; }
    else if (blk < 3344) { W=w6; K=512; N=64;  Kpad=512; Npad=128; dbase=790528;  lstart=3088; sc=s512; }
    else if (blk < 4496) { W=w7; K=576; N=512; Kpad=576; Npad=512; dbase=856064;  lstart=3344; sc=s576; }
    else                 { W=w8; K=512; N=512; Kpad=512; Npad=512; dbase=1150976; lstart=4496; sc=s512; }
    int local = (blk - lstart) * 256 + threadIdx.x;
    int n = local % Npad, k = local / Npad;
    if (k >= Kpad) return;
    float v = (k < K && n < N) ? W[(size_t)k * N + n] * sc : 0.0f;
    wbuf[dbase + (size_t)n * Kpad + k] = f2bf(v);
}

// -------------------------------------------------------------------------
// CSR: scan, fill, wave-bitonic per-segment sort (deterministic)
// -------------------------------------------------------------------------
__global__ __launch_bounds__(1024)
void scan_kernel(const int* __restrict__ deg, int* __restrict__ offs)
{
    __shared__ int part[1024];
    int t = threadIdx.x;
    int base = t * 10;
    int loc[10];
    int s = 0;
    #pragma unroll
    for (int i = 0; i < 10; ++i) {
        int idx = base + i;
        int d = (idx < N_NODES) ? deg[idx] : 0;
        loc[i] = s; s += d;
    }
    part[t] = s;
    __syncthreads();
    for (int o = 1; o < 1024; o <<= 1) {
        int v = (t >= o) ? part[t - o] : 0;
        __syncthreads();
        part[t] += v;
        __syncthreads();
    }
    int excl = (t > 0) ? part[t - 1] : 0;
    #pragma unroll
    for (int i = 0; i < 10; ++i) {
        int idx = base + i;
        if (idx < N_NODES) offs[idx] = excl + loc[i];
    }
    if (t == 1023) offs[N_NODES] = part[1023];
}

__global__ __launch_bounds__(256)
void fill_kernel(const int* __restrict__ ei, const int* __restrict__ offs,
                 int* __restrict__ cnt, int* __restrict__ elist)
{
    int e = blockIdx.x * blockDim.x + threadIdx.x;
    if (e >= E_EDGES) return;
    int c = ei[e];
    int pos = offs[c] + atomicAdd(&cnt[c], 1);
    elist[pos] = e;
}

__global__ __launch_bounds__(256)
void sortseg_kernel(const int* __restrict__ offs, int* __restrict__ elist)
{
    int node = blockIdx.x * 4 + (threadIdx.x >> 6);
    int l = threadIdx.x & 63;
    if (node >= N_NODES) return;
    int b = offs[node], en = offs[node + 1];
    int deg = en - b;
    if (deg <= 1) return;
    if (deg <= 64) {
        int v = (l < deg) ? elist[b + l] : 0x7fffffff;
        #pragma unroll
        for (int k = 2; k <= 64; k <<= 1) {
            #pragma unroll
            for (int j = k >> 1; j > 0; j >>= 1) {
                int o = __shfl_xor(v, j);
                bool dirUp = ((l & k) == 0);
                bool lower = ((l & j) == 0);
                int mn = v < o ? v : o;
                int mx = v < o ? o : v;
                v = (dirUp == lower) ? mn : mx;
            }
        }
        if (l < deg) elist[b + l] = v;
    } else if (l == 0) {
        for (int i = b + 1; i < en; ++i) {
            int v = elist[i];
            int j = i - 1;
            while (j >= b && elist[j] > v) { elist[j + 1] = elist[j]; --j; }
            elist[j + 1] = v;
        }
    }
}

// -------------------------------------------------------------------------
// env gather-sum (plain stores)
// -------------------------------------------------------------------------
__global__ __launch_bounds__(256)
void envgather_kernel(const unsigned short* __restrict__ Wb, int wstride, int woff,
                      const float* __restrict__ ea, const int* __restrict__ offs,
                      const int* __restrict__ elist, float* __restrict__ env)
{
    int n = blockIdx.x * 2 + (threadIdx.x >> 7);
    int t = threadIdx.x & 127;
    if (n >= N_NODES) return;
    int u = t >> 2, comp = t & 3;
    int widx = woff + u * 2 + (comp ? 1 : 0);
    int beg = offs[n], end = offs[n + 1];
    float acc = 0.0f;
    for (int i = beg; i < end; ++i) {
        int e = elist[i];
        float w = bf2f(Wb[(size_t)e * wstride + widx]);
        float a = ea[(size_t)e * 4 + comp];
        acc += a * w;
    }
    env[(size_t)n * 128 + t] = acc * 0.25f;   // 1/sqrt(16)
}

// -------------------------------------------------------------------------
// FUSED two-body MLP + env-embed-0 (round-11 proven, correctness-verified):
// Lb = cut * (silu(silu(A16 @ W0) @ W1) @ W2);  R1b = Lb @ Wenv0
// -------------------------------------------------------------------------
__global__ __launch_bounds__(512)
void mlp2b(const unsigned short* __restrict__ A16b,
           const unsigned short* __restrict__ W0t,   // [128][32]
           const unsigned short* __restrict__ W1t,   // [256][128]
           const unsigned short* __restrict__ W2t,   // [512][256]
           const unsigned short* __restrict__ Wet,   // Wenv0t [128][512]
           const float* __restrict__ cut,
           unsigned short* __restrict__ Lb,
           unsigned short* __restrict__ R1b)
{
    __shared__ __align__(16) unsigned short SA[64 * 32];
    __shared__ __align__(16) unsigned short RG[64 * 512];   // H1 | H2 overlay; Lb slab
    unsigned short* H1 = RG;            // 64 x 128
    unsigned short* H2 = RG + 8192;     // 64 x 256
    const int tid  = threadIdx.x;
    const int lane = tid & 63;
    const int wid  = tid >> 6;
    const int l15  = lane & 15;
    const int l4r  = lane >> 2;
    const int lk8  = (lane >> 4) << 3;
    const int sk8  = (((lane & 3) ^ ((lane >> 3) & 3)) << 3);
    const int rk8  = ((((lane >> 4) ^ ((l15 >> 1) & 3)) & 3) << 3);
    const int bm   = blockIdx.x * 64;
    const int hrow4 = (lane >> 4) << 2;

    if (wid < 4) {
        int row = (wid << 4) + l4r;
        gload16(A16b + (size_t)(bm + row) * 32 + sk8, &SA[wid << 9]);
    }
    asm volatile("s_waitcnt vmcnt(0)" ::: "memory");
    __builtin_amdgcn_s_barrier();
    __builtin_amdgcn_sched_barrier(0);

    // ---- stage A: H1[64][128] = silu(A @ W0^T)
    {
        int hc = wid * 16 + l15;
        bf16x8 wf = __builtin_bit_cast(bf16x8, *(const u32x4*)(W0t + (size_t)hc * 32 + lk8));
        #pragma unroll
        for (int mi = 0; mi < 4; ++mi) {
            bf16x8 af = __builtin_bit_cast(bf16x8, *(const u32x4*)&SA[(mi * 16 + l15) * 32 + rk8]);
            f32x4 a = {};
            a = __builtin_amdgcn_mfma_f32_16x16x32_bf16(af, wf, a, 0, 0, 0);
            #pragma unroll
            for (int rr = 0; rr < 4; ++rr) {
                int er = mi * 16 + hrow4 + rr;
                H1[er * 128 + (((hc >> 3) ^ (er & 7)) << 3) + (hc & 7)] = f2bf(siluf(a[rr]));
            }
        }
    }
    asm volatile("s_waitcnt lgkmcnt(0)" ::: "memory");
    __builtin_amdgcn_s_barrier();
    __builtin_amdgcn_sched_barrier(0);

    // ---- stage B: H2[64][256] = silu(H1 @ W1^T)
    {
        f32x4 acc[4][2] = {};
        #pragma unroll
        for (int kt = 0; kt < 4; ++kt) {
            bf16x8 hf[4], wf[2];
            #pragma unroll
            for (int fa = 0; fa < 4; ++fa) {
                int er = fa * 16 + l15;
                int slotp = (kt * 4 + (lane >> 4)) ^ (er & 7);
                hf[fa] = __builtin_bit_cast(bf16x8, *(const u32x4*)&H1[er * 128 + slotp * 8]);
            }
            #pragma unroll
            for (int fb = 0; fb < 2; ++fb) {
                int hc = wid * 32 + fb * 16 + l15;
                wf[fb] = __builtin_bit_cast(bf16x8, *(const u32x4*)(W1t + (size_t)hc * 128 + kt * 32 + lk8));
            }
            #pragma unroll
            for (int fa = 0; fa < 4; ++fa)
                #pragma unroll
                for (int fb = 0; fb < 2; ++fb)
                    acc[fa][fb] = __builtin_amdgcn_mfma_f32_16x16x32_bf16(hf[fa], wf[fb], acc[fa][fb], 0, 0, 0);
        }
        asm volatile("s_waitcnt lgkmcnt(0)" ::: "memory");
        __builtin_amdgcn_s_barrier();   // all H1 reads done before H2 writes
        #pragma unroll
        for (int fa = 0; fa < 4; ++fa)
            #pragma unroll
            for (int fb = 0; fb < 2; ++fb)
                #pragma unroll
                for (int rr = 0; rr < 4; ++rr) {
                    int er = fa * 16 + hrow4 + rr;
                    int hc = wid * 32 + fb * 16 + l15;
                    H2[er * 256 + (((hc >> 3) ^ (er & 7)) << 3) + (hc & 7)] = f2bf(siluf(acc[fa][fb][rr]));
                }
    }
    asm volatile("s_waitcnt lgkmcnt(0)" ::: "memory");
    __builtin_amdgcn_s_barrier();
    __builtin_amdgcn_sched_barrier(0);

    // ---- stage C: O[64][512] = cut * (H2 @ W2^T)
    f32x4 acc[4][4] = {};
    #pragma unroll 1
    for (int kt = 0; kt < 8; ++kt) {
        bf16x8 hf[4], wf[4];
        #pragma unroll
        for (int fa = 0; fa < 4; ++fa) {
            int er = fa * 16 + l15;
            int slotp = (kt * 4 + (lane >> 4)) ^ (er & 7);
            hf[fa] = __builtin_bit_cast(bf16x8, *(const u32x4*)&H2[er * 256 + slotp * 8]);
        }
        #pragma unroll
        for (int fb = 0; fb < 4; ++fb) {
            int oc = wid * 64 + fb * 16 + l15;
            wf[fb] = __builtin_bit_cast(bf16x8, *(const u32x4*)(W2t + (size_t)oc * 256 + kt * 32 + lk8));
        }
        __builtin_amdgcn_s_setprio(1);
        #pragma unroll
        for (int fa = 0; fa < 4; ++fa)
            #pragma unroll
            for (int fb = 0; fb < 4; ++fb)
                acc[fa][fb] = __builtin_amdgcn_mfma_f32_16x16x32_bf16(hf[fa], wf[fb], acc[fa][fb], 0, 0, 0);
        __builtin_amdgcn_s_setprio(0);
    }
    asm volatile("s_waitcnt lgkmcnt(0)" ::: "memory");
    __builtin_amdgcn_s_barrier();        // all H2 reads done before Lb-slab overwrite
    __builtin_amdgcn_sched_barrier(0);

    // ---- write Lb (global) + Lb slab (LDS, swizzled, overlays RG)
    #pragma unroll
    for (int fa = 0; fa < 4; ++fa) {
        int rbase = bm + fa * 16 + hrow4;
        #pragma unroll
        for (int fb = 0; fb < 4; ++fb) {
            int col = wid * 64 + fb * 16 + l15;
            #pragma unroll
            for (int rr = 0; rr < 4; ++rr) {
                int row = rbase + rr;
                int er  = fa * 16 + hrow4 + rr;
                float v = acc[fa][fb][rr] * cut[row];
                unsigned short b = f2bf(v);
                Lb[(size_t)row * 512 + col] = b;
                RG[er * 512 + (((col >> 3) ^ (er & 7)) << 3) + (col & 7)] = b;
            }
        }
    }
    asm volatile("s_waitcnt lgkmcnt(0)" ::: "memory");
    __builtin_amdgcn_s_barrier();
    __builtin_amdgcn_sched_barrier(0);

    // ---- env-embed 0: R1b[64][128] = LbTile @ Wenv0^T; wave owns 16 cols
    {
        f32x4 acce[4] = {};
        int oc = wid * 16 + l15;
        #pragma unroll 1
        for (int kt = 0; kt < 16; ++kt) {
            bf16x8 wfe = __builtin_bit_cast(bf16x8, *(const u32x4*)(Wet + (size_t)oc * 512 + kt * 32 + lk8));
            #pragma unroll
            for (int fa = 0; fa < 4; ++fa) {
                int er = fa * 16 + l15;
                int slotp = (kt * 4 + (lane >> 4)) ^ (er & 7);
                bf16x8 afe = __builtin_bit_cast(bf16x8, *(const u32x4*)&RG[er * 512 + slotp * 8]);
                acce[fa] = __builtin_amdgcn_mfma_f32_16x16x32_bf16(afe, wfe, acce[fa], 0, 0, 0);
            }
        }
        #pragma unroll
        for (int fa = 0; fa < 4; ++fa) {
            int rbase = bm + fa * 16 + hrow4;
            #pragma unroll
            for (int rr = 0; rr < 4; ++rr)
                R1b[(size_t)(rbase + rr) * 128 + wid * 16 + l15] = f2bf(acce[fa][rr]);
        }
    }
}

// -------------------------------------------------------------------------
// FUSED two-layer MLP, EPIL3 + env-embed-1 (SEPARATE kernel, no template
// sharing — rule-19 isolation). Round-14 proven main loops (W1 staged via
// gload_lds into stage-1-dead Hl slab, vmcnt(5), unpinned) + round-11 tail.
// -------------------------------------------------------------------------
__global__ __launch_bounds__(512)
void fused_mlp3env(const unsigned short* __restrict__ A1,   // Lb [E,512]
                   const unsigned short* __restrict__ A2,   // scalb [E,64]
                   const unsigned short* __restrict__ W1t,  // [512][576]
                   const unsigned short* __restrict__ W2t,  // [512][512]
                   const unsigned short* __restrict__ Wet,  // Wenv1t [128][512]
                   unsigned short* __restrict__ Cb,         // Lb (in place)
                   unsigned short* __restrict__ Weo,        // WE1b [E,64]
                   const float* __restrict__ cut, const float* __restrict__ rp)
{
    __shared__ __align__(16) unsigned short Hl[128 * 512];
    __shared__ __align__(16) unsigned short SA[3][128 * 32];
    const int tid  = threadIdx.x;
    const int lane = tid & 63;
    const int wid  = tid >> 6;
    const int l15  = lane & 15;
    const int l4r  = lane >> 2;
    const int lk8  = (lane >> 4) << 3;
    const int sk8  = (((lane & 3) ^ ((lane >> 3) & 3)) << 3);
    const int rk8  = ((((lane >> 4) ^ ((l15 >> 1) & 3)) & 3) << 3);
    const int bm   = blockIdx.x * 128;
    const int col0 = wid * 64;
    const int hrow4 = (lane >> 4) << 2;

    auto stageA = [&](int t, int b) {
        int k0 = t << 5;
        int row = (wid << 4) + l4r;
        const unsigned short* gp;
        if (k0 < 512) gp = A1 + (size_t)(bm + row) * 512 + k0 + sk8;
        else          gp = A2 + (size_t)(bm + row) * 64 + (k0 - 512) + sk8;
        gload16(gp, &SA[b][wid << 9]);
    };
    auto stageW = [&](int t, int b) {
        int k0 = t << 5;
        #pragma unroll
        for (int i = 0; i < 4; ++i) {
            int ch  = (wid << 2) + i;
            int row = (ch << 4) + l4r;
            gload16(W1t + (size_t)row * 576 + k0 + sk8, &Hl[b * 16384 + (ch << 9)]);
        }
    };

    f32x4 acc1[8][4] = {};
    stageA(0, 0); stageW(0, 0);
    stageA(1, 1); stageW(1, 1);

    for (int t = 0; t < 18; ++t) {
        if (t < 17) asm volatile("s_waitcnt vmcnt(5)" ::: "memory");
        else        asm volatile("s_waitcnt vmcnt(0)" ::: "memory");
        __builtin_amdgcn_s_barrier();
        __builtin_amdgcn_sched_barrier(0);

        if (t + 2 < 18) { stageA(t + 2, (t + 2) % 3); stageW(t + 2, (t + 2) % 3); }

        const unsigned short* As = &SA[t % 3][0];
        const unsigned short* Ws = &Hl[(t % 3) * 16384];
        bf16x8 af[8], wf[4];
        #pragma unroll
        for (int mi = 0; mi < 8; ++mi)
            af[mi] = __builtin_bit_cast(bf16x8, *(const u32x4*)&As[(mi * 16 + l15) * 32 + rk8]);
        #pragma unroll
        for (int ni = 0; ni < 4; ++ni)
            wf[ni] = __builtin_bit_cast(bf16x8, *(const u32x4*)&Ws[(col0 + ni * 16 + l15) * 32 + rk8]);

        __builtin_amdgcn_s_setprio(1);
        #pragma unroll
        for (int mi = 0; mi < 8; ++mi)
            #pragma unroll
            for (int ni = 0; ni < 4; ++ni)
                acc1[mi][ni] = __builtin_amdgcn_mfma_f32_16x16x32_bf16(af[mi], wf[ni], acc1[mi][ni], 0, 0, 0);
        __builtin_amdgcn_s_setprio(0);
    }
    asm volatile("s_waitcnt lgkmcnt(0)" ::: "memory");
    __builtin_amdgcn_s_barrier();
    __builtin_amdgcn_sched_barrier(0);

    // silu + H to swizzled LDS
    #pragma unroll
    for (int mi = 0; mi < 8; ++mi)
        #pragma unroll
        for (int ni = 0; ni < 4; ++ni)
            #pragma unroll
            for (int rr = 0; rr < 4; ++rr) {
                int er = mi * 16 + hrow4 + rr;
                int hc = col0 + ni * 16 + l15;
                Hl[er * 512 + (((hc >> 3) ^ (er & 7)) << 3) + (hc & 7)] = f2bf(siluf(acc1[mi][ni][rr]));
            }
    asm volatile("s_waitcnt lgkmcnt(0)" ::: "memory");
    __builtin_amdgcn_s_barrier();
    __builtin_amdgcn_sched_barrier(0);

    // stage 2
    f32x4 acc2[8][4] = {};
    #pragma unroll 1
    for (int kt = 0; kt < 16; ++kt) {
        bf16x8 hf[8], w2f[4];
        #pragma unroll
        for (int fa = 0; fa < 8; ++fa) {
            int er = fa * 16 + l15;
            int slotp = (kt * 4 + (lane >> 4)) ^ (er & 7);
            hf[fa] = __builtin_bit_cast(bf16x8, *(const u32x4*)&Hl[er * 512 + slotp * 8]);
        }
        #pragma unroll
        for (int fb = 0; fb < 4; ++fb) {
            int oc = col0 + fb * 16 + l15;
            w2f[fb] = __builtin_bit_cast(bf16x8, *(const u32x4*)(W2t + (size_t)oc * 512 + kt * 32 + lk8));
        }
        __builtin_amdgcn_s_setprio(1);
        #pragma unroll
        for (int fa = 0; fa < 8; ++fa)
            #pragma unroll
            for (int fb = 0; fb < 4; ++fb)
                acc2[fa][fb] = __builtin_amdgcn_mfma_f32_16x16x32_bf16(hf[fa], w2f[fb], acc2[fa][fb], 0, 0, 0);
        __builtin_amdgcn_s_setprio(0);
    }

    // all Hl reads retired before overwrite with newLb
    asm volatile("s_waitcnt lgkmcnt(0)" ::: "memory");
    __builtin_amdgcn_s_barrier();
    __builtin_amdgcn_sched_barrier(0);

    // resnet epilogue: write Cb (global) + newLb into Hl slab
    float c0 = __expf(rp[0]), c1 = __expf(rp[1]);
    #pragma unroll
    for (int fa = 0; fa < 8; ++fa) {
        int rbase = bm + fa * 16 + hrow4;
        #pragma unroll
        for (int fb = 0; fb < 4; ++fb) {
            int col = col0 + fb * 16 + l15;
            #pragma unroll
            for (int rr = 0; rr < 4; ++rr) {
                int row = rbase + rr;
                int er  = fa * 16 + hrow4 + rr;
                float v = acc2[fa][fb][rr];
                size_t off2 = (size_t)row * 512 + col;
                float old = bf2f(Cb[off2]);
                v = (c0 * old + c1 * v * cut[row]) * rsqrtf(c0 * c0 + c1 * c1);
                unsigned short b = f2bf(v);
                Cb[off2] = b;
                Hl[er * 512 + (((col >> 3) ^ (er & 7)) << 3) + (col & 7)] = b;
            }
        }
    }
    asm volatile("s_waitcnt lgkmcnt(0)" ::: "memory");
    __builtin_amdgcn_s_barrier();
    __builtin_amdgcn_sched_barrier(0);

    // env-embed 1: WE1b[128][64] = newLb @ Wenv1^T; wave owns 16 rows
    {
        f32x4 acce[4] = {};
        int er = wid * 16 + l15;
        #pragma unroll 1
        for (int kt = 0; kt < 16; ++kt) {
            int slotp = (kt * 4 + (lane >> 4)) ^ (er & 7);
            bf16x8 afe = __builtin_bit_cast(bf16x8, *(const u32x4*)&Hl[er * 512 + slotp * 8]);
            #pragma unroll
            for (int fb = 0; fb < 4; ++fb) {
                int oc = fb * 16 + l15;
                bf16x8 wfe = __builtin_bit_cast(bf16x8, *(const u32x4*)(Wet + (size_t)oc * 512 + kt * 32 + lk8));
                acce[fb] = __builtin_amdgcn_mfma_f32_16x16x32_bf16(afe, wfe, acce[fb], 0, 0, 0);
            }
        }
        #pragma unroll
        for (int fb = 0; fb < 4; ++fb) {
            int col = fb * 16 + l15;
            #pragma unroll
            for (int rr = 0; rr < 4; ++rr) {
                int row = bm + wid * 16 + hrow4 + rr;
                Weo[(size_t)row * 64 + col] = f2bf(acce[fb][rr]);
            }
        }
    }
}

// -------------------------------------------------------------------------
// FUSED two-layer MLP, EPIL4 (SEPARATE kernel — rule-19 isolation).
// Byte-identical structure to round-14's fused_mlp<4>.
// -------------------------------------------------------------------------
__global__ __launch_bounds__(512)
void fused_mlp4(const unsigned short* __restrict__ A1,   // Lb [E,512]
                const unsigned short* __restrict__ A2,   // scalb [E,64]
                const unsigned short* __restrict__ W1t,  // [512][576]
                const unsigned short* __restrict__ W2t,  // [512][512]
                float* __restrict__ Cf, const unsigned short* __restrict__ Cb,
                const float* __restrict__ cut, const float* __restrict__ rp)
{
    __shared__ __align__(16) unsigned short Hl[128 * 512];
    __shared__ __align__(16) unsigned short SA[3][128 * 32];
    const int tid  = threadIdx.x;
    const int lane = tid & 63;
    const int wid  = tid >> 6;
    const int l15  = lane & 15;
    const int l4r  = lane >> 2;
    const int lk8  = (lane >> 4) << 3;
    const int sk8  = (((lane & 3) ^ ((lane >> 3) & 3)) << 3);
    const int rk8  = ((((lane >> 4) ^ ((l15 >> 1) & 3)) & 3) << 3);
    const int bm   = blockIdx.x * 128;
    const int col0 = wid * 64;
    const int hrow4 = (lane >> 4) << 2;

    auto stageA = [&](int t, int b) {
        int k0 = t << 5;
        int row = (wid << 4) + l4r;
        const unsigned short* gp;
        if (k0 < 512) gp = A1 + (size_t)(bm + row) * 512 + k0 + sk8;
        else          gp = A2 + (size_t)(bm + row) * 64 + (k0 - 512) + sk8;
        gload16(gp, &SA[b][wid << 9]);
    };
    auto stageW = [&](int t, int b) {
        int k0 = t << 5;
        #pragma unroll
        for (int i = 0; i < 4; ++i) {
            int ch  = (wid << 2) + i;
            int row = (ch << 4) + l4r;
            gload16(W1t + (size_t)row * 576 + k0 + sk8, &Hl[b * 16384 + (ch << 9)]);
        }
    };

    f32x4 acc1[8][4] = {};
    stageA(0, 0); stageW(0, 0);
    stageA(1, 1); stageW(1, 1);

    for (int t = 0; t < 18; ++t) {
        if (t < 17) asm volatile("s_waitcnt vmcnt(5)" ::: "memory");
        else        asm volatile("s_waitcnt vmcnt(0)" ::: "memory");
        __builtin_amdgcn_s_barrier();
        __builtin_amdgcn_sched_barrier(0);

        if (t + 2 < 18) { stageA(t + 2, (t + 2) % 3); stageW(t + 2, (t + 2) % 3); }

        const unsigned short* As = &SA[t % 3][0];
        const unsigned short* Ws = &Hl[(t % 3) * 16384];
        bf16x8 af[8], wf[4];
        #pragma unroll
        for (int mi = 0; mi < 8; ++mi)
            af[mi] = __builtin_bit_cast(bf16x8, *(const u32x4*)&As[(mi * 16 + l15) * 32 + rk8]);
        #pragma unroll
        for (int ni = 0; ni < 4; ++ni)
            wf[ni] = __builtin_bit_cast(bf16x8, *(const u32x4*)&Ws[(col0 + ni * 16 + l15) * 32 + rk8]);

        __builtin_amdgcn_s_setprio(1);
        #pragma unroll
        for (int mi = 0; mi < 8; ++mi)
            #pragma unroll
            for (int ni = 0; ni < 4; ++ni)
                acc1[mi][ni] = __builtin_amdgcn_mfma_f32_16x16x32_bf16(af[mi], wf[ni], acc1[mi][ni], 0, 0, 0);
        __builtin_amdgcn_s_setprio(0);
    }
    asm volatile("s_waitcnt lgkmcnt(0)" ::: "memory");
    __builtin_amdgcn_s_barrier();
    __builtin_amdgcn_sched_barrier(0);

    #pragma unroll
    for (int mi = 0; mi < 8; ++mi)
        #pragma unroll
        for (int ni = 0; ni < 4; ++ni)
            #pragma unroll
            for (int rr = 0; rr < 4; ++rr) {
                int er = mi * 16 + hrow4 + rr;
                int hc = col0 + ni * 16 + l15;
                Hl[er * 512 + (((hc >> 3) ^ (er & 7)) << 3) + (hc & 7)] = f2bf(siluf(acc1[mi][ni][rr]));
            }
    asm volatile("s_waitcnt lgkmcnt(0)" ::: "memory");
    __builtin_amdgcn_s_barrier();
    __builtin_amdgcn_sched_barrier(0);

    f32x4 acc2[8][4] = {};
    #pragma unroll 1
    for (int kt = 0; kt < 16; ++kt) {
        bf16x8 hf[8], w2f[4];
        #pragma unroll
        for (int fa = 0; fa < 8; ++fa) {
            int er = fa * 16 + l15;
            int slotp = (kt * 4 + (lane >> 4)) ^ (er & 7);
            hf[fa] = __builtin_bit_cast(bf16x8, *(const u32x4*)&Hl[er * 512 + slotp * 8]);
        }
        #pragma unroll
        for (int fb = 0; fb < 4; ++fb) {
            int oc = col0 + fb * 16 + l15;
            w2f[fb] = __builtin_bit_cast(bf16x8, *(const u32x4*)(W2t + (size_t)oc * 512 + kt * 32 + lk8));
        }
        __builtin_amdgcn_s_setprio(1);
        #pragma unroll
        for (int fa = 0; fa < 8; ++fa)
            #pragma unroll
            for (int fb = 0; fb < 4; ++fb)
                acc2[fa][fb] = __builtin_amdgcn_mfma_f32_16x16x32_bf16(hf[fa], w2f[fb], acc2[fa][fb], 0, 0, 0);
        __builtin_amdgcn_s_setprio(0);
    }

    float c0 = __expf(rp[0]), c1 = __expf(rp[1]), c2 = __expf(rp[2]);
    #pragma unroll
    for (int fa = 0; fa < 8; ++fa) {
        int rbase = bm + fa * 16 + hrow4;
        #pragma unroll
        for (int fb = 0; fb < 4; ++fb) {
            int col = col0 + fb * 16 + l15;
            #pragma unroll
            for (int rr = 0; rr < 4; ++rr) {
                int row = rbase + rr;
                float v = acc2[fa][fb][rr];
                size_t off2 = (size_t)row * 512 + col;
                float old = bf2f(Cb[off2]);
                float n2 = c0 * c0 + c1 * c1;
                v = (sqrtf(n2) * old + c2 * v * cut[row]) * rsqrtf(n2 + c2 * c2);
                Cf[off2] = v;
            }
        }
    }
}

// -------------------------------------------------------------------------
// TP0 + e3nn Linear; Ws/Wv staged in LDS with alpha folded
// -------------------------------------------------------------------------
__global__ __launch_bounds__(256)
void tp0_kernel(const unsigned short* __restrict__ W0b, const float* __restrict__ ea,
                const float* __restrict__ env, const int* __restrict__ ei,
                const float* __restrict__ Ws, const float* __restrict__ Wv,
                unsigned short* __restrict__ scalb, unsigned short* __restrict__ feat2b)
{
    __shared__ float sc[8][64];
    __shared__ float xv[8][64][3];
    __shared__ float Wsl[2048];
    __shared__ float Wvl[2048];
    int tid = threadIdx.x;
    const float alpha = 0.125f;  // 1/sqrt(2U)
    #pragma unroll
    for (int i = 0; i < 8; ++i) {
        Wsl[tid + i * 256] = Ws[tid + i * 256] * alpha;
        Wvl[tid + i * 256] = Wv[tid + i * 256] * alpha;
    }
    int le = tid >> 5;
    int u  = tid & 31;
    int e  = blockIdx.x * 8 + le;
    int c  = ei[e];
    float4 a = *(const float4*)(ea + (size_t)e * 4);
    const float* ep = env + (size_t)c * 128 + u * 4;
    float e0 = ep[0], e1 = ep[1], e2 = ep[2], e3 = ep[3];
    float wf0 = bf2f(W0b[(size_t)e * 128 + u * 2]);
    float wf1 = bf2f(W0b[(size_t)e * 128 + u * 2 + 1]);
    float f0 = a.x * wf0;
    float f1 = a.y * wf1, f2 = a.z * wf1, f3 = a.w * wf1;
    const float rs3 = 0.57735026918962576f;
    float t0 = f0 * e0;
    float t1 = (f1 * e1 + f2 * e2 + f3 * e3) * rs3;
    scalb[(size_t)e * 64 + u]      = f2bf(t0);
    scalb[(size_t)e * 64 + 32 + u] = f2bf(t1);
    sc[le][u]      = t0;
    sc[le][32 + u] = t1;
    xv[le][u][0] = f0 * e1; xv[le][u][1] = f0 * e2; xv[le][u][2] = f0 * e3;
    xv[le][32 + u][0] = f1 * e0; xv[le][32 + u][1] = f2 * e0; xv[le][32 + u][2] = f3 * e0;
    __syncthreads();
    float ys = 0.0f, yv0 = 0.0f, yv1 = 0.0f, yv2 = 0.0f;
    #pragma unroll 8
    for (int k = 0; k < 64; ++k) {
        float ws = Wsl[k * 32 + u];
        float wv = Wvl[k * 32 + u];
        ys  = fmaf(sc[le][k], ws, ys);
        yv0 = fmaf(xv[le][k][0], wv, yv0);
        yv1 = fmaf(xv[le][k][1], wv, yv1);
        yv2 = fmaf(xv[le][k][2], wv, yv2);
    }
    ushort4 ov;
    ov.x = f2bf(ys);
    ov.y = f2bf(yv0);
    ov.z = f2bf(yv1);
    ov.w = f2bf(yv2);
    *(ushort4*)(feat2b + (size_t)e * 128 + u * 4) = ov;
}

// -------------------------------------------------------------------------
// TP1 (scalar outputs only) -> scalars2 bf16 [E,64]
// -------------------------------------------------------------------------
__global__ __launch_bounds__(256)
void tp1_kernel(const unsigned short* __restrict__ feat2b, const float* __restrict__ env,
                const int* __restrict__ ei, unsigned short* __restrict__ scalb)
{
    int idx = blockIdx.x * blockDim.x + threadIdx.x;
    if (idx >= E_EDGES * 32) return;
    int e = idx >> 5, u = idx & 31;
    int c = ei[e];
    const float* ep = env + (size_t)c * 128 + u * 4;
    ushort4 f4 = *(const ushort4*)(feat2b + (size_t)e * 128 + u * 4);
    float fx = bf2f(f4.x), fy = bf2f(f4.y), fz = bf2f(f4.z), fw = bf2f(f4.w);
    const float rs3 = 0.57735026918962576f;
    float t0 = fx * ep[0];
    float t1 = (fy * ep[1] + fz * ep[2] + fw * ep[3]) * rs3;
    scalb[(size_t)e * 64 + u]      = f2bf(t0);
    scalb[(size_t)e * 64 + 32 + u] = f2bf(t1);
}

// -------------------------------------------------------------------------
extern "C" void kernel_launch(void* const* d_in, const int* in_sizes, int n_in,
                              void* d_out, int out_size, void* d_ws, size_t ws_size,
                              hipStream_t stream)
{
    const int*   ei     = (const int*)d_in[0];
    const float* na     = (const float*)d_in[1];
    const float* ea     = (const float*)d_in[2];
    const float* embed  = (const float*)d_in[3];
    const float* elen   = (const float*)d_in[4];
    const float* W2b0   = (const float*)d_in[5];
    const float* W2b1   = (const float*)d_in[6];
    const float* W2b2   = (const float*)d_in[7];
    const float* Wenv0  = (const float*)d_in[8];
    const float* Wlat0  = (const float*)d_in[9];
    const float* Wlat1  = (const float*)d_in[10];
    const float* Wenv1  = (const float*)d_in[11];
    const float* Wfin0  = (const float*)d_in[12];
    const float* Wfin1  = (const float*)d_in[13];
    const float* Wlin_s = (const float*)d_in[14];
    const float* Wlin_v = (const float*)d_in[15];
    const float* rp     = (const float*)d_in[16];

    float* L = (float*)d_out;   // final f32 latents (fused_mlp4 writes once)
    const size_t E = E_EDGES;

    char* ws = (char*)d_ws;
    size_t off = 0;
    auto alloc = [&](size_t b) { void* p = ws + off; off += (b + 255) & ~(size_t)255; return p; };
    float*          cutb   = (float*)alloc(E * 4);
    unsigned short* wbuf   = (unsigned short*)alloc((size_t)1413120 * 2);
    float*          envb   = (float*)alloc((size_t)N_NODES * 128 * 4);
    unsigned short* scalb  = (unsigned short*)alloc(E * 64 * 2);
    unsigned short* feat2b = (unsigned short*)alloc(E * 128 * 2);
    unsigned short* Lb     = (unsigned short*)alloc(E * 512 * 2);
    int*            degcnt = (int*)alloc((size_t)2 * N_NODES * 4);
    int*            offs   = (int*)alloc((N_NODES + 1) * 4);
    int*            elist  = (int*)alloc(E * 4);
    unsigned short* A16b   = (unsigned short*)alloc(E * 32 * 2);
    unsigned short* R1b    = (unsigned short*)alloc(E * 128 * 2);
    unsigned short* WE1b   = (unsigned short*)alloc(E * 64 * 2);
    int* deg = degcnt;
    int* cnt = degcnt + N_NODES;

    unsigned short* W2b0t  = wbuf;
    unsigned short* W2b1t  = wbuf + 4096;
    unsigned short* W2b2t  = wbuf + 36864;
    unsigned short* Wenv0t = wbuf + 167936;
    unsigned short* Wlat0t = wbuf + 233472;
    unsigned short* Wlat1t = wbuf + 528384;
    unsigned short* Wenv1t = wbuf + 790528;
    unsigned short* Wfin0t = wbuf + 856064;
    unsigned short* Wfin1t = wbuf + 1150976;
    wtrans_all<<<5520, 256, 0, stream>>>(W2b0, W2b1, W2b2, Wenv0, Wlat0, Wlat1,
                                         Wenv1, Wfin0, Wfin1, wbuf);

    hipMemsetAsync(degcnt, 0, (size_t)2 * N_NODES * 4, stream);
    prep_kernel<<<E_EDGES / 256, 256, 0, stream>>>(ei, na, embed, elen, cutb, A16b, deg);
    scan_kernel<<<1, 1024, 0, stream>>>(deg, offs);
    fill_kernel<<<E_EDGES / 256, 256, 0, stream>>>(ei, offs, cnt, elist);
    sortseg_kernel<<<N_NODES / 4, 256, 0, stream>>>(offs, elist);

    // ---- FUSED two-body MLP + env0: -> Lb, R1b
    mlp2b<<<2500, 512, 0, stream>>>(A16b, W2b0t, W2b1t, W2b2t, Wenv0t, cutb, Lb, R1b);

    envgather_kernel<<<N_NODES / 2, 256, 0, stream>>>(R1b, 128, 64, ea, offs, elist, envb);
    tp0_kernel<<<E_EDGES / 8, 256, 0, stream>>>(R1b, ea, envb, ei, Wlin_s, Wlin_v, scalb, feat2b);

    // ---- FUSED latent resnet MLP + env1: -> Lb (in place), WE1b
    fused_mlp3env<<<1250, 512, 0, stream>>>(Lb, scalb, Wlat0t, Wlat1t, Wenv1t,
                                            Lb, WE1b, cutb, rp);

    envgather_kernel<<<N_NODES / 2, 256, 0, stream>>>(WE1b, 64, 0, ea, offs, elist, envb);
    tp1_kernel<<<E_EDGES * 32 / 256, 256, 0, stream>>>(feat2b, envb, ei, scalb);

    // ---- FUSED final MLP: -> f32 d_out
    fused_mlp4<<<1250, 512, 0, stream>>>(Lb, scalb, Wfin0t, Wfin1t, L, Lb, cutb, rp);
}

// Round 18
// 1066.486 us; speedup vs baseline: 4.7532x; 1.1284x over previous
//
#include <hip/hip_runtime.h>
#include <math.h>

#define E_EDGES 160000
#define N_NODES 10000

typedef __attribute__((ext_vector_type(8))) __bf16 bf16x8;
typedef __attribute__((ext_vector_type(4))) float f32x4;
typedef __attribute__((ext_vector_type(4))) unsigned int u32x4;

__device__ __forceinline__ unsigned short f2bf(float x) {
    unsigned u = __float_as_uint(x);
    u += 0x7fff + ((u >> 16) & 1);   // round-to-nearest-even
    return (unsigned short)(u >> 16);
}
__device__ __forceinline__ float bf2f(unsigned short h) {
    return __uint_as_float(((unsigned)h) << 16);
}
__device__ __forceinline__ float siluf(float v) {
    return v / (1.0f + __expf(-v));
}
__device__ __forceinline__ void gload16(const unsigned short* g, unsigned short* l) {
    __builtin_amdgcn_global_load_lds(
        (const __attribute__((address_space(1))) void*)g,
        (__attribute__((address_space(3))) void*)l, 16, 0, 0);
}

// -------------------------------------------------------------------------
// prep (+degree histogram): cutoff + 16-dim two-body rows (bf16, K pad 32)
// -------------------------------------------------------------------------
__global__ __launch_bounds__(256)
void prep_kernel(const int* __restrict__ ei, const float* __restrict__ na,
                 const float* __restrict__ embed, const float* __restrict__ elen,
                 float* __restrict__ cut, unsigned short* __restrict__ A16b,
                 int* __restrict__ deg)
{
    int e = blockIdx.x * blockDim.x + threadIdx.x;
    if (e >= E_EDGES) return;
    float r  = elen[e];
    float x  = r * (1.0f / 6.0f);
    float x2 = x * x;
    float x6 = x2 * x2 * x2;
    float c = 1.0f - 28.0f * x6 + 48.0f * x6 * x - 21.0f * x6 * x2;
    cut[e] = (x < 1.0f) ? c : 0.0f;
    int ctr = ei[e];
    int ngh = ei[E_EDGES + e];
    atomicAdd(&deg[ctr], 1);
    float4 ac = *(const float4*)(na + (size_t)ctr * 4);
    float4 an = *(const float4*)(na + (size_t)ngh * 4);
    float4 b0 = *(const float4*)(embed + (size_t)e * 8);
    float4 b1 = *(const float4*)(embed + (size_t)e * 8 + 4);
    unsigned short* o = A16b + (size_t)e * 32;
    o[0]  = f2bf(ac.x); o[1]  = f2bf(ac.y); o[2]  = f2bf(ac.z); o[3]  = f2bf(ac.w);
    o[4]  = f2bf(an.x); o[5]  = f2bf(an.y); o[6]  = f2bf(an.z); o[7]  = f2bf(an.w);
    o[8]  = f2bf(b0.x); o[9]  = f2bf(b0.y); o[10] = f2bf(b0.z); o[11] = f2bf(b0.w);
    o[12] = f2bf(b1.x); o[13] = f2bf(b1.y); o[14] = f2bf(b1.z); o[15] = f2bf(b1.w);
    #pragma unroll
    for (int i = 16; i < 32; ++i) o[i] = 0;
}

// -------------------------------------------------------------------------
// all 9 weight transposes in one grid; scale folded. Bt[n*Kpad+k]=W[k*N+n]*sc
// -------------------------------------------------------------------------
__global__ __launch_bounds__(256)
void wtrans_all(const float* __restrict__ w0, const float* __restrict__ w1,
                const float* __restrict__ w2, const float* __restrict__ w3,
                const float* __restrict__ w4, const float* __restrict__ w5,
                const float* __restrict__ w6, const float* __restrict__ w7,
                const float* __restrict__ w8, unsigned short* __restrict__ wbuf)
{
    int blk = blockIdx.x;
    const float* W; int K, N, Kpad, Npad; size_t dbase; int lstart; float sc;
    const float s16  = 0.25f;
    const float s128 = 0.088388347648318447f;
    const float s256 = 0.0625f;
    const float s512 = 0.044194173824159223f;
    const float s576 = 0.041666666666666664f;
    if      (blk <   16) { W=w0; K=16;  N=128; Kpad=32;  Npad=128; dbase=0;       lstart=0;    sc=s16;  }
    else if (blk <  144) { W=w1; K=128; N=256; Kpad=128; Npad=256; dbase=4096;    lstart=16;   sc=s128; }
    else if (blk <  656) { W=w2; K=256; N=512; Kpad=256; Npad=512; dbase=36864;   lstart=144;  sc=s256; }
    else if (blk <  912) { W=w3; K=512; N=128; Kpad=512; Npad=128; dbase=167936;  lstart=656;  sc=s512; }
    else if (blk < 2064) { W=w4; K=576; N=512; Kpad=576; Npad=512; dbase=233472;  lstart=912;  sc=s576; }
    else if (blk < 3088) { W=w5; K=512; N=512; Kpad=512; Npad=512; dbase=528384;  lstart=2064; sc=s512; }
    else if (blk < 3344) { W=w6; K=512; N=64;  Kpad=512; Npad=128; dbase=790528;  lstart=3088; sc=s512; }
    else if (blk < 4496) { W=w7; K=576; N=512; Kpad=576; Npad=512; dbase=856064;  lstart=3344; sc=s576; }
    else                 { W=w8; K=512; N=512; Kpad=512; Npad=512; dbase=1150976; lstart=4496; sc=s512; }
    int local = (blk - lstart) * 256 + threadIdx.x;
    int n = local % Npad, k = local / Npad;
    if (k >= Kpad) return;
    float v = (k < K && n < N) ? W[(size_t)k * N + n] * sc : 0.0f;
    wbuf[dbase + (size_t)n * Kpad + k] = f2bf(v);
}

// -------------------------------------------------------------------------
// CSR: scan, fill, wave-bitonic per-segment sort (deterministic)
// -------------------------------------------------------------------------
__global__ __launch_bounds__(1024)
void scan_kernel(const int* __restrict__ deg, int* __restrict__ offs)
{
    __shared__ int part[1024];
    int t = threadIdx.x;
    int base = t * 10;
    int loc[10];
    int s = 0;
    #pragma unroll
    for (int i = 0; i < 10; ++i) {
        int idx = base + i;
        int d = (idx < N_NODES) ? deg[idx] : 0;
        loc[i] = s; s += d;
    }
    part[t] = s;
    __syncthreads();
    for (int o = 1; o < 1024; o <<= 1) {
        int v = (t >= o) ? part[t - o] : 0;
        __syncthreads();
        part[t] += v;
        __syncthreads();
    }
    int excl = (t > 0) ? part[t - 1] : 0;
    #pragma unroll
    for (int i = 0; i < 10; ++i) {
        int idx = base + i;
        if (idx < N_NODES) offs[idx] = excl + loc[i];
    }
    if (t == 1023) offs[N_NODES] = part[1023];
}

__global__ __launch_bounds__(256)
void fill_kernel(const int* __restrict__ ei, const int* __restrict__ offs,
                 int* __restrict__ cnt, int* __restrict__ elist)
{
    int e = blockIdx.x * blockDim.x + threadIdx.x;
    if (e >= E_EDGES) return;
    int c = ei[e];
    int pos = offs[c] + atomicAdd(&cnt[c], 1);
    elist[pos] = e;
}

__global__ __launch_bounds__(256)
void sortseg_kernel(const int* __restrict__ offs, int* __restrict__ elist)
{
    int node = blockIdx.x * 4 + (threadIdx.x >> 6);
    int l = threadIdx.x & 63;
    if (node >= N_NODES) return;
    int b = offs[node], en = offs[node + 1];
    int deg = en - b;
    if (deg <= 1) return;
    if (deg <= 64) {
        int v = (l < deg) ? elist[b + l] : 0x7fffffff;
        #pragma unroll
        for (int k = 2; k <= 64; k <<= 1) {
            #pragma unroll
            for (int j = k >> 1; j > 0; j >>= 1) {
                int o = __shfl_xor(v, j);
                bool dirUp = ((l & k) == 0);
                bool lower = ((l & j) == 0);
                int mn = v < o ? v : o;
                int mx = v < o ? o : v;
                v = (dirUp == lower) ? mn : mx;
            }
        }
        if (l < deg) elist[b + l] = v;
    } else if (l == 0) {
        for (int i = b + 1; i < en; ++i) {
            int v = elist[i];
            int j = i - 1;
            while (j >= b && elist[j] > v) { elist[j + 1] = elist[j]; --j; }
            elist[j + 1] = v;
        }
    }
}

// -------------------------------------------------------------------------
// env gather-sum (plain stores)
// -------------------------------------------------------------------------
__global__ __launch_bounds__(256)
void envgather_kernel(const unsigned short* __restrict__ Wb, int wstride, int woff,
                      const float* __restrict__ ea, const int* __restrict__ offs,
                      const int* __restrict__ elist, float* __restrict__ env)
{
    int n = blockIdx.x * 2 + (threadIdx.x >> 7);
    int t = threadIdx.x & 127;
    if (n >= N_NODES) return;
    int u = t >> 2, comp = t & 3;
    int widx = woff + u * 2 + (comp ? 1 : 0);
    int beg = offs[n], end = offs[n + 1];
    float acc = 0.0f;
    for (int i = beg; i < end; ++i) {
        int e = elist[i];
        float w = bf2f(Wb[(size_t)e * wstride + widx]);
        float a = ea[(size_t)e * 4 + comp];
        acc += a * w;
    }
    env[(size_t)n * 128 + t] = acc * 0.25f;   // 1/sqrt(16)
}

// -------------------------------------------------------------------------
// bf16 MFMA GEMM: 128x128 tile, BK=32, 4 waves, 3 LDS pairs, counted-vmcnt
// depth-2 pipeline, ONE barrier/iter, XOR swizzle, unpinned inner loop.
// -------------------------------------------------------------------------
template<int EPIL>
__global__ __launch_bounds__(256)
void gemm_bf16(const unsigned short* __restrict__ A1,
               int K, const unsigned short* __restrict__ Bt,
               int nx, int ldc, int Nstore,
               unsigned short* __restrict__ Cb)
{
    __shared__ __align__(16) unsigned short SB[3][2][128 * 32];
    const int tid  = threadIdx.x;
    const int lane = tid & 63;
    const int wid  = tid >> 6;
    const int wr   = wid >> 1, wc = wid & 1;
    const int nwg = gridDim.x;
    const int fid = blockIdx.x;
    const int q = nwg >> 3, r = nwg & 7;
    const int xcd = fid & 7, j = fid >> 3;
    const int L = ((xcd < r) ? xcd * (q + 1) : r * (q + 1) + (xcd - r) * q) + j;
    const int bn = (L % nx) * 128;
    const int bm = (L / nx) * 128;

    const int l15 = lane & 15;
    const int l4r = lane >> 2;
    const int sk8 = (((lane & 3) ^ ((lane >> 3) & 3)) << 3);
    const int rk8 = ((((lane >> 4) ^ ((l15 >> 1) & 3)) & 3) << 3);
    const int T   = K >> 5;

    f32x4 acc[4][4] = {};

    auto stage = [&](int t, int b) {
        int k0 = t << 5;
        #pragma unroll
        for (int i = 0; i < 2; ++i) {
            int ch  = (wid << 1) + i;
            int row = (ch << 4) + l4r;
            gload16(A1 + (size_t)(bm + row) * K + k0 + sk8, &SB[b][0][ch << 9]);
            gload16(Bt + (size_t)(bn + row) * K + k0 + sk8, &SB[b][1][ch << 9]);
        }
    };

    stage(0, 0);
    if (T >= 2) stage(1, 1);

    for (int t = 0; t < T; ++t) {
        if (t < T - 1) asm volatile("s_waitcnt vmcnt(4)" ::: "memory");
        else           asm volatile("s_waitcnt vmcnt(0)" ::: "memory");
        __builtin_amdgcn_s_barrier();
        __builtin_amdgcn_sched_barrier(0);

        if (t + 2 < T) stage(t + 2, (t + 2) % 3);

        const unsigned short* As = &SB[t % 3][0][0];
        const unsigned short* Bs = &SB[t % 3][1][0];
        bf16x8 af[4], bfr[4];
        #pragma unroll
        for (int m = 0; m < 4; ++m)
            af[m] = __builtin_bit_cast(bf16x8, *(const u32x4*)&As[(wr * 64 + m * 16 + l15) * 32 + rk8]);
        #pragma unroll
        for (int n = 0; n < 4; ++n)
            bfr[n] = __builtin_bit_cast(bf16x8, *(const u32x4*)&Bs[(wc * 64 + n * 16 + l15) * 32 + rk8]);

        __builtin_amdgcn_s_setprio(1);
        #pragma unroll
        for (int m = 0; m < 4; ++m)
            #pragma unroll
            for (int n = 0; n < 4; ++n)
                acc[m][n] = __builtin_amdgcn_mfma_f32_16x16x32_bf16(af[m], bfr[n], acc[m][n], 0, 0, 0);
        __builtin_amdgcn_s_setprio(0);
    }

    #pragma unroll
    for (int m = 0; m < 4; ++m) {
        int rbase = bm + wr * 64 + m * 16 + ((lane >> 4) << 2);
        #pragma unroll
        for (int n = 0; n < 4; ++n) {
            int col = bn + wc * 64 + n * 16 + l15;
            if (col < Nstore) {
                #pragma unroll
                for (int rr = 0; rr < 4; ++rr) {
                    int row = rbase + rr;
                    Cb[(size_t)row * ldc + col] = f2bf(acc[m][n][rr]);
                }
            }
        }
    }
}

// -------------------------------------------------------------------------
// FUSED two-body MLP (round-10 proven): Lb = cut * (silu(silu(A16@W0)@W1)@W2)
// -------------------------------------------------------------------------
__global__ __launch_bounds__(512)
void mlp2b(const unsigned short* __restrict__ A16b,
           const unsigned short* __restrict__ W0t,   // [128][32]
           const unsigned short* __restrict__ W1t,   // [256][128]
           const unsigned short* __restrict__ W2t,   // [512][256]
           const float* __restrict__ cut, unsigned short* __restrict__ Lb)
{
    __shared__ __align__(16) unsigned short SA[64 * 32];
    __shared__ __align__(16) unsigned short H1[64 * 128];
    __shared__ __align__(16) unsigned short H2[64 * 256];
    const int tid  = threadIdx.x;
    const int lane = tid & 63;
    const int wid  = tid >> 6;
    const int l15  = lane & 15;
    const int l4r  = lane >> 2;
    const int lk8  = (lane >> 4) << 3;
    const int sk8  = (((lane & 3) ^ ((lane >> 3) & 3)) << 3);
    const int rk8  = ((((lane >> 4) ^ ((l15 >> 1) & 3)) & 3) << 3);
    const int bm   = blockIdx.x * 64;
    const int hrow4 = (lane >> 4) << 2;

    if (wid < 4) {
        int row = (wid << 4) + l4r;
        gload16(A16b + (size_t)(bm + row) * 32 + sk8, &SA[wid << 9]);
    }
    asm volatile("s_waitcnt vmcnt(0)" ::: "memory");
    __builtin_amdgcn_s_barrier();
    __builtin_amdgcn_sched_barrier(0);

    // ---- stage A: H1[64][128] = silu(A @ W0^T)
    {
        int hc = wid * 16 + l15;
        bf16x8 wf = __builtin_bit_cast(bf16x8, *(const u32x4*)(W0t + (size_t)hc * 32 + lk8));
        #pragma unroll
        for (int mi = 0; mi < 4; ++mi) {
            bf16x8 af = __builtin_bit_cast(bf16x8, *(const u32x4*)&SA[(mi * 16 + l15) * 32 + rk8]);
            f32x4 a = {};
            a = __builtin_amdgcn_mfma_f32_16x16x32_bf16(af, wf, a, 0, 0, 0);
            #pragma unroll
            for (int rr = 0; rr < 4; ++rr) {
                int er = mi * 16 + hrow4 + rr;
                H1[er * 128 + (((hc >> 3) ^ (er & 7)) << 3) + (hc & 7)] = f2bf(siluf(a[rr]));
            }
        }
    }
    asm volatile("s_waitcnt lgkmcnt(0)" ::: "memory");
    __builtin_amdgcn_s_barrier();
    __builtin_amdgcn_sched_barrier(0);

    // ---- stage B: H2[64][256] = silu(H1 @ W1^T)
    {
        f32x4 acc[4][2] = {};
        #pragma unroll
        for (int kt = 0; kt < 4; ++kt) {
            bf16x8 hf[4], wf[2];
            #pragma unroll
            for (int fa = 0; fa < 4; ++fa) {
                int er = fa * 16 + l15;
                int slotp = (kt * 4 + (lane >> 4)) ^ (er & 7);
                hf[fa] = __builtin_bit_cast(bf16x8, *(const u32x4*)&H1[er * 128 + slotp * 8]);
            }
            #pragma unroll
            for (int fb = 0; fb < 2; ++fb) {
                int hc = wid * 32 + fb * 16 + l15;
                wf[fb] = __builtin_bit_cast(bf16x8, *(const u32x4*)(W1t + (size_t)hc * 128 + kt * 32 + lk8));
            }
            #pragma unroll
            for (int fa = 0; fa < 4; ++fa)
                #pragma unroll
                for (int fb = 0; fb < 2; ++fb)
                    acc[fa][fb] = __builtin_amdgcn_mfma_f32_16x16x32_bf16(hf[fa], wf[fb], acc[fa][fb], 0, 0, 0);
        }
        asm volatile("s_waitcnt lgkmcnt(0)" ::: "memory");
        __builtin_amdgcn_s_barrier();
        #pragma unroll
        for (int fa = 0; fa < 4; ++fa)
            #pragma unroll
            for (int fb = 0; fb < 2; ++fb)
                #pragma unroll
                for (int rr = 0; rr < 4; ++rr) {
                    int er = fa * 16 + hrow4 + rr;
                    int hc = wid * 32 + fb * 16 + l15;
                    H2[er * 256 + (((hc >> 3) ^ (er & 7)) << 3) + (hc & 7)] = f2bf(siluf(acc[fa][fb][rr]));
                }
    }
    asm volatile("s_waitcnt lgkmcnt(0)" ::: "memory");
    __builtin_amdgcn_s_barrier();
    __builtin_amdgcn_sched_barrier(0);

    // ---- stage C: O[64][512] = cut * (H2 @ W2^T)
    f32x4 acc[4][4] = {};
    #pragma unroll 1
    for (int kt = 0; kt < 8; ++kt) {
        bf16x8 hf[4], wf[4];
        #pragma unroll
        for (int fa = 0; fa < 4; ++fa) {
            int er = fa * 16 + l15;
            int slotp = (kt * 4 + (lane >> 4)) ^ (er & 7);
            hf[fa] = __builtin_bit_cast(bf16x8, *(const u32x4*)&H2[er * 256 + slotp * 8]);
        }
        #pragma unroll
        for (int fb = 0; fb < 4; ++fb) {
            int oc = wid * 64 + fb * 16 + l15;
            wf[fb] = __builtin_bit_cast(bf16x8, *(const u32x4*)(W2t + (size_t)oc * 256 + kt * 32 + lk8));
        }
        __builtin_amdgcn_s_setprio(1);
        #pragma unroll
        for (int fa = 0; fa < 4; ++fa)
            #pragma unroll
            for (int fb = 0; fb < 4; ++fb)
                acc[fa][fb] = __builtin_amdgcn_mfma_f32_16x16x32_bf16(hf[fa], wf[fb], acc[fa][fb], 0, 0, 0);
        __builtin_amdgcn_s_setprio(0);
    }
    #pragma unroll
    for (int fa = 0; fa < 4; ++fa) {
        int rbase = bm + fa * 16 + hrow4;
        #pragma unroll
        for (int fb = 0; fb < 4; ++fb) {
            int col = wid * 64 + fb * 16 + l15;
            #pragma unroll
            for (int rr = 0; rr < 4; ++rr) {
                int row = rbase + rr;
                Lb[(size_t)row * 512 + col] = f2bf(acc[fa][fb][rr] * cut[row]);
            }
        }
    }
}

// -------------------------------------------------------------------------
// FUSED two-layer MLP (128 rows, 8 waves), W1 staged via gload_lds into the
// stage-1-dead Hl slab (3x32KB), counted vmcnt(5) depth-2 pipeline, unpinned.
// EPIL2: 3 = resnet1 -> Lb bf16 (in-place), 4 = resnet2 -> L f32
// -------------------------------------------------------------------------
template<int EPIL2>
__global__ __launch_bounds__(512)
void fused_mlp(const unsigned short* __restrict__ A1,   // Lb [E,512]
               const unsigned short* __restrict__ A2,   // scalb [E,64]
               const unsigned short* __restrict__ W1t,  // [512][576]
               const unsigned short* __restrict__ W2t,  // [512][512]
               float* __restrict__ Cf, unsigned short* __restrict__ Cb,
               const float* __restrict__ cut, const float* __restrict__ rp)
{
    __shared__ __align__(16) unsigned short Hl[128 * 512];   // 128 KB; [0,96KB) = W staging in stage 1
    __shared__ __align__(16) unsigned short SA[3][128 * 32]; // 3 x 8 KB A staging
    const int tid  = threadIdx.x;
    const int lane = tid & 63;
    const int wid  = tid >> 6;            // 0..7
    const int l15  = lane & 15;
    const int l4r  = lane >> 2;
    const int lk8  = (lane >> 4) << 3;    // k sub-offset (shorts)
    const int sk8  = (((lane & 3) ^ ((lane >> 3) & 3)) << 3);
    const int rk8  = ((((lane >> 4) ^ ((l15 >> 1) & 3)) & 3) << 3);
    const int bm   = blockIdx.x * 128;
    const int col0 = wid * 64;
    const int hrow4 = (lane >> 4) << 2;

    auto stageA = [&](int t, int b) {
        int k0 = t << 5;
        int row = (wid << 4) + l4r;
        const unsigned short* gp;
        if (k0 < 512) gp = A1 + (size_t)(bm + row) * 512 + k0 + sk8;
        else          gp = A2 + (size_t)(bm + row) * 64 + (k0 - 512) + sk8;
        gload16(gp, &SA[b][wid << 9]);
    };
    auto stageW = [&](int t, int b) {
        int k0 = t << 5;
        #pragma unroll
        for (int i = 0; i < 4; ++i) {
            int ch  = (wid << 2) + i;          // 0..31
            int row = (ch << 4) + l4r;         // hc 0..511
            gload16(W1t + (size_t)row * 576 + k0 + sk8, &Hl[b * 16384 + (ch << 9)]);
        }
    };

    f32x4 acc1[8][4] = {};
    stageA(0, 0); stageW(0, 0);
    stageA(1, 1); stageW(1, 1);

    for (int t = 0; t < 18; ++t) {
        if (t < 17) asm volatile("s_waitcnt vmcnt(5)" ::: "memory");
        else        asm volatile("s_waitcnt vmcnt(0)" ::: "memory");
        __builtin_amdgcn_s_barrier();
        __builtin_amdgcn_sched_barrier(0);

        if (t + 2 < 18) { stageA(t + 2, (t + 2) % 3); stageW(t + 2, (t + 2) % 3); }

        const unsigned short* As = &SA[t % 3][0];
        const unsigned short* Ws = &Hl[(t % 3) * 16384];
        bf16x8 af[8], wf[4];
        #pragma unroll
        for (int mi = 0; mi < 8; ++mi)
            af[mi] = __builtin_bit_cast(bf16x8, *(const u32x4*)&As[(mi * 16 + l15) * 32 + rk8]);
        #pragma unroll
        for (int ni = 0; ni < 4; ++ni)
            wf[ni] = __builtin_bit_cast(bf16x8, *(const u32x4*)&Ws[(col0 + ni * 16 + l15) * 32 + rk8]);

        __builtin_amdgcn_s_setprio(1);
        #pragma unroll
        for (int mi = 0; mi < 8; ++mi)
            #pragma unroll
            for (int ni = 0; ni < 4; ++ni)
                acc1[mi][ni] = __builtin_amdgcn_mfma_f32_16x16x32_bf16(af[mi], wf[ni], acc1[mi][ni], 0, 0, 0);
        __builtin_amdgcn_s_setprio(0);
    }
    asm volatile("s_waitcnt lgkmcnt(0)" ::: "memory");
    __builtin_amdgcn_s_barrier();        // all waves' W-slab reads retired; safe to overwrite Hl
    __builtin_amdgcn_sched_barrier(0);

    // --- silu + write H to swizzled LDS
    #pragma unroll
    for (int mi = 0; mi < 8; ++mi)
        #pragma unroll
        for (int ni = 0; ni < 4; ++ni)
            #pragma unroll
            for (int rr = 0; rr < 4; ++rr) {
                int er = mi * 16 + hrow4 + rr;
                int hc = col0 + ni * 16 + l15;
                Hl[er * 512 + (((hc >> 3) ^ (er & 7)) << 3) + (hc & 7)] = f2bf(siluf(acc1[mi][ni][rr]));
            }
    asm volatile("s_waitcnt lgkmcnt(0)" ::: "memory");
    __builtin_amdgcn_s_barrier();
    __builtin_amdgcn_sched_barrier(0);

    // --- stage 2: barrier-free; H frags from LDS, W2 frags from L2
    f32x4 acc2[8][4] = {};
    #pragma unroll 1
    for (int kt = 0; kt < 16; ++kt) {
        bf16x8 hf[8], w2f[4];
        #pragma unroll
        for (int fa = 0; fa < 8; ++fa) {
            int er = fa * 16 + l15;
            int slotp = (kt * 4 + (lane >> 4)) ^ (er & 7);
            hf[fa] = __builtin_bit_cast(bf16x8, *(const u32x4*)&Hl[er * 512 + slotp * 8]);
        }
        #pragma unroll
        for (int fb = 0; fb < 4; ++fb) {
            int oc = col0 + fb * 16 + l15;
            w2f[fb] = __builtin_bit_cast(bf16x8, *(const u32x4*)(W2t + (size_t)oc * 512 + kt * 32 + lk8));
        }
        __builtin_amdgcn_s_setprio(1);
        #pragma unroll
        for (int fa = 0; fa < 8; ++fa)
            #pragma unroll
            for (int fb = 0; fb < 4; ++fb)
                acc2[fa][fb] = __builtin_amdgcn_mfma_f32_16x16x32_bf16(hf[fa], w2f[fb], acc2[fa][fb], 0, 0, 0);
        __builtin_amdgcn_s_setprio(0);
    }

    // --- resnet epilogue (coalesced)
    float c0 = __expf(rp[0]), c1 = __expf(rp[1]), c2 = __expf(rp[2]);
    #pragma unroll
    for (int fa = 0; fa < 8; ++fa) {
        int rbase = bm + fa * 16 + hrow4;
        #pragma unroll
        for (int fb = 0; fb < 4; ++fb) {
            int col = col0 + fb * 16 + l15;
            #pragma unroll
            for (int rr = 0; rr < 4; ++rr) {
                int row = rbase + rr;
                float v = acc2[fa][fb][rr];
                size_t off2 = (size_t)row * 512 + col;
                if (EPIL2 == 3) {
                    float old = bf2f(Cb[off2]);
                    v = (c0 * old + c1 * v * cut[row]) * rsqrtf(c0 * c0 + c1 * c1);
                    Cb[off2] = f2bf(v);
                } else {
                    float old = bf2f(Cb[off2]);
                    float n2 = c0 * c0 + c1 * c1;
                    v = (sqrtf(n2) * old + c2 * v * cut[row]) * rsqrtf(n2 + c2 * c2);
                    Cf[off2] = v;
                }
            }
        }
    }
}

// -------------------------------------------------------------------------
// TP0 + e3nn Linear; Ws/Wv staged in LDS with alpha folded
// -------------------------------------------------------------------------
__global__ __launch_bounds__(256)
void tp0_kernel(const unsigned short* __restrict__ W0b, const float* __restrict__ ea,
                const float* __restrict__ env, const int* __restrict__ ei,
                const float* __restrict__ Ws, const float* __restrict__ Wv,
                unsigned short* __restrict__ scalb, unsigned short* __restrict__ feat2b)
{
    __shared__ float sc[8][64];
    __shared__ float xv[8][64][3];
    __shared__ float Wsl[2048];
    __shared__ float Wvl[2048];
    int tid = threadIdx.x;
    const float alpha = 0.125f;  // 1/sqrt(2U)
    #pragma unroll
    for (int i = 0; i < 8; ++i) {
        Wsl[tid + i * 256] = Ws[tid + i * 256] * alpha;
        Wvl[tid + i * 256] = Wv[tid + i * 256] * alpha;
    }
    int le = tid >> 5;
    int u  = tid & 31;
    int e  = blockIdx.x * 8 + le;
    int c  = ei[e];
    float4 a = *(const float4*)(ea + (size_t)e * 4);
    const float* ep = env + (size_t)c * 128 + u * 4;
    float e0 = ep[0], e1 = ep[1], e2 = ep[2], e3 = ep[3];
    float wf0 = bf2f(W0b[(size_t)e * 128 + u * 2]);
    float wf1 = bf2f(W0b[(size_t)e * 128 + u * 2 + 1]);
    float f0 = a.x * wf0;
    float f1 = a.y * wf1, f2 = a.z * wf1, f3 = a.w * wf1;
    const float rs3 = 0.57735026918962576f;
    float t0 = f0 * e0;
    float t1 = (f1 * e1 + f2 * e2 + f3 * e3) * rs3;
    scalb[(size_t)e * 64 + u]      = f2bf(t0);
    scalb[(size_t)e * 64 + 32 + u] = f2bf(t1);
    sc[le][u]      = t0;
    sc[le][32 + u] = t1;
    xv[le][u][0] = f0 * e1; xv[le][u][1] = f0 * e2; xv[le][u][2] = f0 * e3;
    xv[le][32 + u][0] = f1 * e0; xv[le][32 + u][1] = f2 * e0; xv[le][32 + u][2] = f3 * e0;
    __syncthreads();
    float ys = 0.0f, yv0 = 0.0f, yv1 = 0.0f, yv2 = 0.0f;
    #pragma unroll 8
    for (int k = 0; k < 64; ++k) {
        float ws = Wsl[k * 32 + u];
        float wv = Wvl[k * 32 + u];
        ys  = fmaf(sc[le][k], ws, ys);
        yv0 = fmaf(xv[le][k][0], wv, yv0);
        yv1 = fmaf(xv[le][k][1], wv, yv1);
        yv2 = fmaf(xv[le][k][2], wv, yv2);
    }
    ushort4 ov;
    ov.x = f2bf(ys);
    ov.y = f2bf(yv0);
    ov.z = f2bf(yv1);
    ov.w = f2bf(yv2);
    *(ushort4*)(feat2b + (size_t)e * 128 + u * 4) = ov;
}

// -------------------------------------------------------------------------
// TP1 (scalar outputs only) -> scalars2 bf16 [E,64]
// -------------------------------------------------------------------------
__global__ __launch_bounds__(256)
void tp1_kernel(const unsigned short* __restrict__ feat2b, const float* __restrict__ env,
                const int* __restrict__ ei, unsigned short* __restrict__ scalb)
{
    int idx = blockIdx.x * blockDim.x + threadIdx.x;
    if (idx >= E_EDGES * 32) return;
    int e = idx >> 5, u = idx & 31;
    int c = ei[e];
    const float* ep = env + (size_t)c * 128 + u * 4;
    ushort4 f4 = *(const ushort4*)(feat2b + (size_t)e * 128 + u * 4);
    float fx = bf2f(f4.x), fy = bf2f(f4.y), fz = bf2f(f4.z), fw = bf2f(f4.w);
    const float rs3 = 0.57735026918962576f;
    float t0 = fx * ep[0];
    float t1 = (fy * ep[1] + fz * ep[2] + fw * ep[3]) * rs3;
    scalb[(size_t)e * 64 + u]      = f2bf(t0);
    scalb[(size_t)e * 64 + 32 + u] = f2bf(t1);
}

// -------------------------------------------------------------------------
extern "C" void kernel_launch(void* const* d_in, const int* in_sizes, int n_in,
                              void* d_out, int out_size, void* d_ws, size_t ws_size,
                              hipStream_t stream)
{
    const int*   ei     = (const int*)d_in[0];
    const float* na     = (const float*)d_in[1];
    const float* ea     = (const float*)d_in[2];
    const float* embed  = (const float*)d_in[3];
    const float* elen   = (const float*)d_in[4];
    const float* W2b0   = (const float*)d_in[5];
    const float* W2b1   = (const float*)d_in[6];
    const float* W2b2   = (const float*)d_in[7];
    const float* Wenv0  = (const float*)d_in[8];
    const float* Wlat0  = (const float*)d_in[9];
    const float* Wlat1  = (const float*)d_in[10];
    const float* Wenv1  = (const float*)d_in[11];
    const float* Wfin0  = (const float*)d_in[12];
    const float* Wfin1  = (const float*)d_in[13];
    const float* Wlin_s = (const float*)d_in[14];
    const float* Wlin_v = (const float*)d_in[15];
    const float* rp     = (const float*)d_in[16];

    float* L = (float*)d_out;   // final f32 latents (fused<4> writes once)
    const size_t E = E_EDGES;

    char* ws = (char*)d_ws;
    size_t off = 0;
    auto alloc = [&](size_t b) { void* p = ws + off; off += (b + 255) & ~(size_t)255; return p; };
    float*          cutb   = (float*)alloc(E * 4);
    unsigned short* wbuf   = (unsigned short*)alloc((size_t)1413120 * 2);
    float*          envb   = (float*)alloc((size_t)N_NODES * 128 * 4);
    unsigned short* scalb  = (unsigned short*)alloc(E * 64 * 2);
    unsigned short* feat2b = (unsigned short*)alloc(E * 128 * 2);
    unsigned short* Lb     = (unsigned short*)alloc(E * 512 * 2);
    int*            degcnt = (int*)alloc((size_t)2 * N_NODES * 4);
    int*            offs   = (int*)alloc((N_NODES + 1) * 4);
    int*            elist  = (int*)alloc(E * 4);
    unsigned short* A16b   = (unsigned short*)alloc(E * 32 * 2);
    unsigned short* R1b    = (unsigned short*)alloc(E * 128 * 2);
    unsigned short* WE1b   = (unsigned short*)alloc(E * 64 * 2);
    int* deg = degcnt;
    int* cnt = degcnt + N_NODES;

    unsigned short* W2b0t  = wbuf;
    unsigned short* W2b1t  = wbuf + 4096;
    unsigned short* W2b2t  = wbuf + 36864;
    unsigned short* Wenv0t = wbuf + 167936;
    unsigned short* Wlat0t = wbuf + 233472;
    unsigned short* Wlat1t = wbuf + 528384;
    unsigned short* Wenv1t = wbuf + 790528;
    unsigned short* Wfin0t = wbuf + 856064;
    unsigned short* Wfin1t = wbuf + 1150976;
    wtrans_all<<<5520, 256, 0, stream>>>(W2b0, W2b1, W2b2, Wenv0, Wlat0, Wlat1,
                                         Wenv1, Wfin0, Wfin1, wbuf);

    hipMemsetAsync(degcnt, 0, (size_t)2 * N_NODES * 4, stream);
    prep_kernel<<<E_EDGES / 256, 256, 0, stream>>>(ei, na, embed, elen, cutb, A16b, deg);
    scan_kernel<<<1, 1024, 0, stream>>>(deg, offs);
    fill_kernel<<<E_EDGES / 256, 256, 0, stream>>>(ei, offs, cnt, elist);
    sortseg_kernel<<<N_NODES / 4, 256, 0, stream>>>(offs, elist);

    // ---- FUSED two-body MLP: A16 -> 128 -> 256 -> 512 (*cut) -> Lb
    mlp2b<<<2500, 512, 0, stream>>>(A16b, W2b0t, W2b1t, W2b2t, cutb, Lb);

    // ---- env-embed 0: R1b = Lb @ Wenv0t  [E,128] bf16
    gemm_bf16<0><<<1250, 256, 0, stream>>>(Lb, 512, Wenv0t, 1, 128, 128, R1b);

    envgather_kernel<<<N_NODES / 2, 256, 0, stream>>>(R1b, 128, 64, ea, offs, elist, envb);
    tp0_kernel<<<E_EDGES / 8, 256, 0, stream>>>(R1b, ea, envb, ei, Wlin_s, Wlin_v, scalb, feat2b);

    // ---- FUSED latent resnet MLP: [Lb|scal](576) -> 512 silu -> 512 -> Lb
    fused_mlp<3><<<1250, 512, 0, stream>>>(Lb, scalb, Wlat0t, Wlat1t, nullptr, Lb, cutb, rp);

    // ---- env-embed 1: WE1b = Lb @ Wenv1t  [E,64] bf16 (N padded 128)
    gemm_bf16<0><<<1250, 256, 0, stream>>>(Lb, 512, Wenv1t, 1, 64, 64, WE1b);

    envgather_kernel<<<N_NODES / 2, 256, 0, stream>>>(WE1b, 64, 0, ea, offs, elist, envb);
    tp1_kernel<<<E_EDGES * 32 / 256, 256, 0, stream>>>(feat2b, envb, ei, scalb);

    // ---- FUSED final MLP: -> f32 d_out
    fused_mlp<4><<<1250, 512, 0, stream>>>(Lb, scalb, Wfin0t, Wfin1t, L, Lb, cutb, rp);
}